// Round 1
// baseline (1737.797 us; speedup 1.0000x reference)
//
#include <hip/hip_runtime.h>
#include <math.h>

#define NB 4
#define DIMM 256
#define DSTATE 16
#define DCONV 4
#define DIN 512
#define DTRANK 16
#define BB 16
#define LL 512
#define TT (BB * LL)            // 8192 tokens
#define XZ_DIM (2 * DIN)        // 1024
#define DBC_DIM (DTRANK + 2 * DSTATE)  // 48

// ---------------- LayerNorm: one block per token, 256 threads ----------------
__global__ __launch_bounds__(256) void ln_kernel(const float* __restrict__ x,
                                                 const float* __restrict__ w,
                                                 const float* __restrict__ bvec,
                                                 float* __restrict__ out) {
    int t = blockIdx.x;
    int i = threadIdx.x;
    float v = x[t * DIMM + i];
    float s = v, s2 = v * v;
#pragma unroll
    for (int off = 1; off < 64; off <<= 1) {
        s  += __shfl_xor(s, off);
        s2 += __shfl_xor(s2, off);
    }
    __shared__ float ss[4], ss2[4];
    int wid = i >> 6;
    if ((i & 63) == 0) { ss[wid] = s; ss2[wid] = s2; }
    __syncthreads();
    s  = ss[0] + ss[1] + ss[2] + ss[3];
    s2 = ss2[0] + ss2[1] + ss2[2] + ss2[3];
    float mu  = s * (1.0f / DIMM);
    float var = s2 * (1.0f / DIMM) - mu * mu;
    float r   = rsqrtf(var + 1e-5f);
    out[t * DIMM + i] = (v - mu) * r * w[i] + bvec[i];
}

// ---------------- Generic tiled NT GEMM: C = A * Bw^T (+bias) (+resid) -------
// A: M x K (row-major, lda), Bw: N x K (row-major, ldb), C: M x N (ldc).
// M must be a multiple of 64 (always 8192 here); K multiple of 16; N ragged ok
// at float4 granularity (all Ns here are multiples of 4).
#define GBM 64
#define GBN 64
#define GBK 16
__global__ __launch_bounds__(256) void gemm_nt(const float* __restrict__ A, int lda,
                                               const float* __restrict__ Bw, int ldb,
                                               const float* __restrict__ bias,
                                               const float* __restrict__ resid,
                                               float* __restrict__ C, int ldc,
                                               int N, int K) {
    __shared__ float As[GBK][GBM + 4];  // k-major so fragment reads are b128
    __shared__ float Bs[GBK][GBN + 4];
    int tid = threadIdx.x;
    int tx = tid & 15;        // 0..15 -> n
    int ty = tid >> 4;        // 0..15 -> m
    int m0 = blockIdx.y * GBM;
    int n0 = blockIdx.x * GBN;
    int lrow = tid >> 2;            // 0..63
    int lcol = (tid & 3) * 4;       // 0,4,8,12

    float acc[4][4] = {};

    for (int k0 = 0; k0 < K; k0 += GBK) {
        // stage A tile (64 rows x 16 k)
        {
            const float4 av = *(const float4*)&A[(size_t)(m0 + lrow) * lda + k0 + lcol];
            As[lcol + 0][lrow] = av.x;
            As[lcol + 1][lrow] = av.y;
            As[lcol + 2][lrow] = av.z;
            As[lcol + 3][lrow] = av.w;
        }
        // stage B tile (64 rows x 16 k), guard ragged N
        {
            int gn = n0 + lrow;
            float4 bv = make_float4(0.f, 0.f, 0.f, 0.f);
            if (gn < N) bv = *(const float4*)&Bw[(size_t)gn * ldb + k0 + lcol];
            Bs[lcol + 0][lrow] = bv.x;
            Bs[lcol + 1][lrow] = bv.y;
            Bs[lcol + 2][lrow] = bv.z;
            Bs[lcol + 3][lrow] = bv.w;
        }
        __syncthreads();
#pragma unroll
        for (int kk = 0; kk < GBK; ++kk) {
            const float4 a = *(const float4*)&As[kk][ty * 4];
            const float4 b = *(const float4*)&Bs[kk][tx * 4];
            const float av[4] = {a.x, a.y, a.z, a.w};
            const float bv[4] = {b.x, b.y, b.z, b.w};
#pragma unroll
            for (int i = 0; i < 4; ++i)
#pragma unroll
                for (int j = 0; j < 4; ++j) acc[i][j] += av[i] * bv[j];
        }
        __syncthreads();
    }

    int n = n0 + tx * 4;
    if (n < N) {
        float4 bb = make_float4(0.f, 0.f, 0.f, 0.f);
        if (bias) bb = *(const float4*)&bias[n];
#pragma unroll
        for (int i = 0; i < 4; ++i) {
            int m = m0 + ty * 4 + i;
            float4 v = make_float4(acc[i][0] + bb.x, acc[i][1] + bb.y,
                                   acc[i][2] + bb.z, acc[i][3] + bb.w);
            if (resid) {
                const float4 rv = *(const float4*)&resid[(size_t)m * ldc + n];
                v.x += rv.x; v.y += rv.y; v.z += rv.z; v.w += rv.w;
            }
            *(float4*)&C[(size_t)m * ldc + n] = v;
        }
    }
}

// ---------------- Depthwise causal conv (4-tap) + SiLU -----------------------
__global__ __launch_bounds__(256) void conv_silu(const float* __restrict__ xz,
                                                 const float* __restrict__ cw,
                                                 const float* __restrict__ cb,
                                                 float* __restrict__ xc) {
    int idx = blockIdx.x * blockDim.x + threadIdx.x;  // over TT*DIN
    int d = idx & (DIN - 1);
    int t = idx >> 9;        // / DIN
    int l = t & (LL - 1);
    int bq = t >> 9;         // / LL
    float acc = cb[d];
#pragma unroll
    for (int k = 0; k < DCONV; ++k) {
        int ls = l - (DCONV - 1) + k;
        if (ls >= 0) acc += cw[d * DCONV + k] * xz[(size_t)(bq * LL + ls) * XZ_DIM + d];
    }
    // silu
    xc[(size_t)t * DIN + d] = acc / (1.0f + __expf(-acc));
}

// ---------------- dt = softplus(dbc[:, :16] @ dtw^T + dtb) -------------------
__global__ __launch_bounds__(256) void dt_kernel(const float* __restrict__ dbc,
                                                 const float* __restrict__ dtw,
                                                 const float* __restrict__ dtbias,
                                                 float* __restrict__ dtout) {
    int idx = blockIdx.x * blockDim.x + threadIdx.x;  // over TT*DIN
    int d = idx & (DIN - 1);
    int t = idx >> 9;
    float a = dtbias[d];
    const float4* wv = (const float4*)(dtw + d * DTRANK);
    const float* dr = dbc + (size_t)t * DBC_DIM;
#pragma unroll
    for (int q = 0; q < 4; ++q) {
        float4 w4 = wv[q];
        a += w4.x * dr[q * 4 + 0] + w4.y * dr[q * 4 + 1] +
             w4.z * dr[q * 4 + 2] + w4.w * dr[q * 4 + 3];
    }
    float sp = (a > 20.0f) ? a : log1pf(__expf(a));
    dtout[(size_t)t * DIN + d] = sp;
}

// ---------------- Selective scan ---------------------------------------------
// grid = BB * (DIN/16) blocks, 256 threads = 16 channels x 16 states.
// Writes y in-place over u (xc buffer).
__global__ __launch_bounds__(256) void scan_kernel(const float* __restrict__ dt,
                                                   float* __restrict__ xc,
                                                   const float* __restrict__ dbc,
                                                   const float* __restrict__ A_log,
                                                   const float* __restrict__ Dp) {
    int b  = blockIdx.x >> 5;        // / 32
    int dg = blockIdx.x & 31;
    int dl = threadIdx.x >> 4;
    int n  = threadIdx.x & 15;
    int d  = dg * 16 + dl;

    float a  = -__expf(A_log[d * DSTATE + n]);
    float Dd = Dp[d];
    float h = 0.0f;
    for (int t = 0; t < LL; ++t) {
        size_t row = (size_t)(b * LL + t);
        float dtv = dt[row * DIN + d];
        float u   = xc[row * DIN + d];
        float bt  = dbc[row * DBC_DIM + DTRANK + n];
        float ct  = dbc[row * DBC_DIM + DTRANK + DSTATE + n];
        float dA  = __expf(dtv * a);
        h = dA * h + dtv * bt * u;
        float yp = h * ct;
        yp += __shfl_xor(yp, 1);
        yp += __shfl_xor(yp, 2);
        yp += __shfl_xor(yp, 4);
        yp += __shfl_xor(yp, 8);
        if (n == 0) xc[row * DIN + d] = yp + u * Dd;
    }
}

// ---------------- g = y * silu(z) --------------------------------------------
__global__ __launch_bounds__(256) void g_kernel(const float* __restrict__ y,
                                                const float* __restrict__ xz,
                                                float* __restrict__ g) {
    int idx = blockIdx.x * blockDim.x + threadIdx.x;  // over TT*DIN
    int d = idx & (DIN - 1);
    int t = idx >> 9;
    float zz = xz[(size_t)t * XZ_DIM + DIN + d];
    float yy = y[(size_t)t * DIN + d];
    g[idx] = yy * (zz / (1.0f + __expf(-zz)));
}

extern "C" void kernel_launch(void* const* d_in, const int* in_sizes, int n_in,
                              void* d_out, int out_size, void* d_ws, size_t ws_size,
                              hipStream_t stream) {
    const float* x_in   = (const float*)d_in[0];
    const float* ln_w   = (const float*)d_in[1];
    const float* ln_b   = (const float*)d_in[2];
    const float* in_w   = (const float*)d_in[3];
    const float* in_b   = (const float*)d_in[4];
    const float* conv_w = (const float*)d_in[5];
    const float* conv_b = (const float*)d_in[6];
    const float* xp_w   = (const float*)d_in[7];
    const float* dt_w   = (const float*)d_in[8];
    const float* dt_b   = (const float*)d_in[9];
    const float* A_log  = (const float*)d_in[10];
    const float* Dp     = (const float*)d_in[11];
    const float* ow     = (const float*)d_in[12];
    float* out = (float*)d_out;

    float* ws   = (float*)d_ws;
    float* xbuf = ws;                         // TT*DIMM
    float* hbuf = xbuf + (size_t)TT * DIMM;   // TT*DIMM (reused as dbc)
    float* xz   = hbuf + (size_t)TT * DIMM;   // TT*1024
    float* xc   = xz   + (size_t)TT * XZ_DIM; // TT*DIN (u, then y in-place)
    float* dtb  = xc   + (size_t)TT * DIN;    // TT*DIN (dt, then g)
    float* dbc  = hbuf;                       // TT*48 fits in TT*256

    for (int layer = 0; layer < NB; ++layer) {
        const float* xi = (layer == 0) ? x_in : xbuf;
        float* xo = (layer == NB - 1) ? out : xbuf;

        ln_kernel<<<TT, 256, 0, stream>>>(xi, ln_w + layer * DIMM, ln_b + layer * DIMM, hbuf);

        // in_proj: (TT x 256) @ (1024 x 256)^T + b -> xz (TT x 1024)
        gemm_nt<<<dim3(XZ_DIM / GBN, TT / GBM), 256, 0, stream>>>(
            hbuf, DIMM, in_w + (size_t)layer * XZ_DIM * DIMM, DIMM,
            in_b + layer * XZ_DIM, nullptr, xz, XZ_DIM, XZ_DIM, DIMM);

        conv_silu<<<(TT * DIN) / 256, 256, 0, stream>>>(
            xz, conv_w + layer * DIN * DCONV, conv_b + layer * DIN, xc);

        // x_proj: (TT x 512) @ (48 x 512)^T -> dbc (TT x 48)
        gemm_nt<<<dim3(1, TT / GBM), 256, 0, stream>>>(
            xc, DIN, xp_w + (size_t)layer * DBC_DIM * DIN, DIN,
            nullptr, nullptr, dbc, DBC_DIM, DBC_DIM, DIN);

        dt_kernel<<<(TT * DIN) / 256, 256, 0, stream>>>(
            dbc, dt_w + (size_t)layer * DIN * DTRANK, dt_b + layer * DIN, dtb);

        scan_kernel<<<BB * (DIN / 16), 256, 0, stream>>>(
            dtb, xc, dbc, A_log + (size_t)layer * DIN * DSTATE, Dp + layer * DIN);

        g_kernel<<<(TT * DIN) / 256, 256, 0, stream>>>(xc, xz, dtb);

        // out_proj: (TT x 512) @ (256 x 512)^T + x -> xo (TT x 256)
        gemm_nt<<<dim3(DIMM / GBN, TT / GBM), 256, 0, stream>>>(
            dtb, DIN, ow + (size_t)layer * DIMM * DIN, DIN,
            nullptr, xi, xo, DIMM, DIMM, DIN);
    }
}

// Round 2
// 1238.919 us; speedup vs baseline: 1.4027x; 1.4027x over previous
//
#include <hip/hip_runtime.h>
#include <math.h>

#define NB 4
#define DIMM 256
#define DSTATE 16
#define DCONV 4
#define DIN 512
#define DTRANK 16
#define BB 16
#define LL 512
#define TT (BB * LL)            // 8192 tokens
#define XZ_DIM (2 * DIN)        // 1024
#define DBC_DIM (DTRANK + 2 * DSTATE)  // 48
#define NC 4                    // scan chunks
#define CHUNK (LL / NC)         // 128

// ---------------- LayerNorm: one block per token, 256 threads ----------------
__global__ __launch_bounds__(256) void ln_kernel(const float* __restrict__ x,
                                                 const float* __restrict__ w,
                                                 const float* __restrict__ bvec,
                                                 float* __restrict__ out) {
    int t = blockIdx.x;
    int i = threadIdx.x;
    float v = x[t * DIMM + i];
    float s = v, s2 = v * v;
#pragma unroll
    for (int off = 1; off < 64; off <<= 1) {
        s  += __shfl_xor(s, off);
        s2 += __shfl_xor(s2, off);
    }
    __shared__ float ss[4], ss2[4];
    int wid = i >> 6;
    if ((i & 63) == 0) { ss[wid] = s; ss2[wid] = s2; }
    __syncthreads();
    s  = ss[0] + ss[1] + ss[2] + ss[3];
    s2 = ss2[0] + ss2[1] + ss2[2] + ss2[3];
    float mu  = s * (1.0f / DIMM);
    float var = s2 * (1.0f / DIMM) - mu * mu;
    float r   = rsqrtf(var + 1e-5f);
    out[t * DIMM + i] = (v - mu) * r * w[i] + bvec[i];
}

// ---------------- Generic tiled NT GEMM: C = A * Bw^T (+bias) (+resid) -------
#define GBM 64
#define GBN 64
#define GBK 16
__global__ __launch_bounds__(256) void gemm_nt(const float* __restrict__ A, int lda,
                                               const float* __restrict__ Bw, int ldb,
                                               const float* __restrict__ bias,
                                               const float* __restrict__ resid,
                                               float* __restrict__ C, int ldc,
                                               int N, int K) {
    __shared__ float As[GBK][GBM + 4];
    __shared__ float Bs[GBK][GBN + 4];
    int tid = threadIdx.x;
    int tx = tid & 15;
    int ty = tid >> 4;
    int m0 = blockIdx.y * GBM;
    int n0 = blockIdx.x * GBN;
    int lrow = tid >> 2;
    int lcol = (tid & 3) * 4;

    float acc[4][4] = {};

    for (int k0 = 0; k0 < K; k0 += GBK) {
        {
            const float4 av = *(const float4*)&A[(size_t)(m0 + lrow) * lda + k0 + lcol];
            As[lcol + 0][lrow] = av.x;
            As[lcol + 1][lrow] = av.y;
            As[lcol + 2][lrow] = av.z;
            As[lcol + 3][lrow] = av.w;
        }
        {
            int gn = n0 + lrow;
            float4 bv = make_float4(0.f, 0.f, 0.f, 0.f);
            if (gn < N) bv = *(const float4*)&Bw[(size_t)gn * ldb + k0 + lcol];
            Bs[lcol + 0][lrow] = bv.x;
            Bs[lcol + 1][lrow] = bv.y;
            Bs[lcol + 2][lrow] = bv.z;
            Bs[lcol + 3][lrow] = bv.w;
        }
        __syncthreads();
#pragma unroll
        for (int kk = 0; kk < GBK; ++kk) {
            const float4 a = *(const float4*)&As[kk][ty * 4];
            const float4 b = *(const float4*)&Bs[kk][tx * 4];
            const float av[4] = {a.x, a.y, a.z, a.w};
            const float bv[4] = {b.x, b.y, b.z, b.w};
#pragma unroll
            for (int i = 0; i < 4; ++i)
#pragma unroll
                for (int j = 0; j < 4; ++j) acc[i][j] += av[i] * bv[j];
        }
        __syncthreads();
    }

    int n = n0 + tx * 4;
    if (n < N) {
        float4 bb = make_float4(0.f, 0.f, 0.f, 0.f);
        if (bias) bb = *(const float4*)&bias[n];
#pragma unroll
        for (int i = 0; i < 4; ++i) {
            int m = m0 + ty * 4 + i;
            float4 v = make_float4(acc[i][0] + bb.x, acc[i][1] + bb.y,
                                   acc[i][2] + bb.z, acc[i][3] + bb.w);
            if (resid) {
                const float4 rv = *(const float4*)&resid[(size_t)m * ldc + n];
                v.x += rv.x; v.y += rv.y; v.z += rv.z; v.w += rv.w;
            }
            *(float4*)&C[(size_t)m * ldc + n] = v;
        }
    }
}

// ---------------- Depthwise causal conv (4-tap) + SiLU -----------------------
__global__ __launch_bounds__(256) void conv_silu(const float* __restrict__ xz,
                                                 const float* __restrict__ cw,
                                                 const float* __restrict__ cb,
                                                 float* __restrict__ xc) {
    int idx = blockIdx.x * blockDim.x + threadIdx.x;
    int d = idx & (DIN - 1);
    int t = idx >> 9;
    int l = t & (LL - 1);
    int bq = t >> 9;
    float acc = cb[d];
#pragma unroll
    for (int k = 0; k < DCONV; ++k) {
        int ls = l - (DCONV - 1) + k;
        if (ls >= 0) acc += cw[d * DCONV + k] * xz[(size_t)(bq * LL + ls) * XZ_DIM + d];
    }
    xc[(size_t)t * DIN + d] = acc / (1.0f + __expf(-acc));
}

// ---------------- dt = softplus(dbc[:, :16] @ dtw^T + dtb) -------------------
__global__ __launch_bounds__(256) void dt_kernel(const float* __restrict__ dbc,
                                                 const float* __restrict__ dtw,
                                                 const float* __restrict__ dtbias,
                                                 float* __restrict__ dtout) {
    int idx = blockIdx.x * blockDim.x + threadIdx.x;
    int d = idx & (DIN - 1);
    int t = idx >> 9;
    float a = dtbias[d];
    const float4* wv = (const float4*)(dtw + d * DTRANK);
    const float* dr = dbc + (size_t)t * DBC_DIM;
#pragma unroll
    for (int q = 0; q < 4; ++q) {
        float4 w4 = wv[q];
        a += w4.x * dr[q * 4 + 0] + w4.y * dr[q * 4 + 1] +
             w4.z * dr[q * 4 + 2] + w4.w * dr[q * 4 + 3];
    }
    float sp = (a > 20.0f) ? a : log1pf(__expf(a));
    dtout[(size_t)t * DIN + d] = sp;
}

// ---------------- Selective scan, chunked (3 phases) -------------------------
// Phase 1: per (b, chunk, d, n): local scan from h=0; emit P = prod(dA), H = final h.
// grid = BB*NC*32 blocks of 256 (16 d x 16 n).
__global__ __launch_bounds__(256) void scan_phase1(const float* __restrict__ dt,
                                                   const float* __restrict__ xc,
                                                   const float* __restrict__ dbc,
                                                   const float* __restrict__ A_log,
                                                   float* __restrict__ P,
                                                   float* __restrict__ H) {
    int bid = blockIdx.x;
    int dg = bid & 31;
    int c  = (bid >> 5) & (NC - 1);
    int b  = bid >> 7;
    int dl = threadIdx.x >> 4;
    int n  = threadIdx.x & 15;
    int d  = dg * 16 + dl;

    float a = -__expf(A_log[d * DSTATE + n]);
    float h = 0.0f, p = 1.0f;
    int t0 = c * CHUNK;
    for (int t = 0; t < CHUNK; ++t) {
        size_t row = (size_t)(b * LL + t0 + t);
        float dtv = dt[row * DIN + d];
        float u   = xc[row * DIN + d];
        float bt  = dbc[row * DBC_DIM + DTRANK + n];
        float dA  = __expf(dtv * a);
        h = dA * h + dtv * bt * u;
        p *= dA;
    }
    size_t idx = (((size_t)b * NC + c) * DIN + d) * DSTATE + n;
    P[idx] = p;
    H[idx] = h;
}

// Phase 2: serial combine over chunks -> carry-in h per chunk.
__global__ __launch_bounds__(256) void scan_phase2(const float* __restrict__ P,
                                                   const float* __restrict__ H,
                                                   float* __restrict__ Hin) {
    int idx = blockIdx.x * 256 + threadIdx.x;   // over BB*DIN*DSTATE = 131072
    int b  = idx >> 13;                          // / 8192
    int dn = idx & 8191;
    float h = 0.0f;
#pragma unroll
    for (int c = 0; c < NC; ++c) {
        size_t q = ((size_t)b * NC + c) * (DIN * DSTATE) + dn;
        Hin[q] = h;
        h = P[q] * h + H[q];
    }
}

// Phase 3: full scan per chunk with h0 = Hin, y written in-place over xc.
__global__ __launch_bounds__(256) void scan_phase3(const float* __restrict__ dt,
                                                   float* __restrict__ xc,
                                                   const float* __restrict__ dbc,
                                                   const float* __restrict__ A_log,
                                                   const float* __restrict__ Dp,
                                                   const float* __restrict__ Hin) {
    int bid = blockIdx.x;
    int dg = bid & 31;
    int c  = (bid >> 5) & (NC - 1);
    int b  = bid >> 7;
    int dl = threadIdx.x >> 4;
    int n  = threadIdx.x & 15;
    int d  = dg * 16 + dl;

    float a  = -__expf(A_log[d * DSTATE + n]);
    float Dd = Dp[d];
    float h  = Hin[(((size_t)b * NC + c) * DIN + d) * DSTATE + n];
    int t0 = c * CHUNK;
    for (int t = 0; t < CHUNK; ++t) {
        size_t row = (size_t)(b * LL + t0 + t);
        float dtv = dt[row * DIN + d];
        float u   = xc[row * DIN + d];
        float bt  = dbc[row * DBC_DIM + DTRANK + n];
        float ct  = dbc[row * DBC_DIM + DTRANK + DSTATE + n];
        float dA  = __expf(dtv * a);
        h = dA * h + dtv * bt * u;
        float yp = h * ct;
        yp += __shfl_xor(yp, 1);
        yp += __shfl_xor(yp, 2);
        yp += __shfl_xor(yp, 4);
        yp += __shfl_xor(yp, 8);
        if (n == 0) xc[row * DIN + d] = yp + u * Dd;
    }
}

// ---------------- g = y * silu(z) --------------------------------------------
__global__ __launch_bounds__(256) void g_kernel(const float* __restrict__ y,
                                                const float* __restrict__ xz,
                                                float* __restrict__ g) {
    int idx = blockIdx.x * blockDim.x + threadIdx.x;
    int d = idx & (DIN - 1);
    int t = idx >> 9;
    float zz = xz[(size_t)t * XZ_DIM + DIN + d];
    float yy = y[(size_t)t * DIN + d];
    g[idx] = yy * (zz / (1.0f + __expf(-zz)));
}

extern "C" void kernel_launch(void* const* d_in, const int* in_sizes, int n_in,
                              void* d_out, int out_size, void* d_ws, size_t ws_size,
                              hipStream_t stream) {
    const float* x_in   = (const float*)d_in[0];
    const float* ln_w   = (const float*)d_in[1];
    const float* ln_b   = (const float*)d_in[2];
    const float* in_w   = (const float*)d_in[3];
    const float* in_b   = (const float*)d_in[4];
    const float* conv_w = (const float*)d_in[5];
    const float* conv_b = (const float*)d_in[6];
    const float* xp_w   = (const float*)d_in[7];
    const float* dt_w   = (const float*)d_in[8];
    const float* dt_b   = (const float*)d_in[9];
    const float* A_log  = (const float*)d_in[10];
    const float* Dp     = (const float*)d_in[11];
    const float* ow     = (const float*)d_in[12];
    float* out = (float*)d_out;

    float* ws   = (float*)d_ws;
    float* xbuf = ws;                         // TT*DIMM
    float* hbuf = xbuf + (size_t)TT * DIMM;   // TT*DIMM region (dbc + scan scratch)
    float* xz   = hbuf + (size_t)TT * DIMM;   // TT*1024
    float* xc   = xz   + (size_t)TT * XZ_DIM; // TT*DIN (u, then y in-place)
    float* dtb  = xc   + (size_t)TT * DIN;    // TT*DIN (dt, then g)
    float* dbc  = hbuf;                       // TT*48
    // scan scratch carved from hbuf tail: TT*48 .. TT*48 + 3*B*NC*DIN*DSTATE
    const size_t SCN = (size_t)BB * NC * DIN * DSTATE;   // 524288
    float* Pbuf  = hbuf + (size_t)TT * DBC_DIM;
    float* Hbuf  = Pbuf + SCN;
    float* Hin   = Hbuf + SCN;   // total 1965984 < TT*256 = 2097152 floats

    for (int layer = 0; layer < NB; ++layer) {
        const float* xi = (layer == 0) ? x_in : xbuf;
        float* xo = (layer == NB - 1) ? out : xbuf;

        ln_kernel<<<TT, 256, 0, stream>>>(xi, ln_w + layer * DIMM, ln_b + layer * DIMM, hbuf);

        gemm_nt<<<dim3(XZ_DIM / GBN, TT / GBM), 256, 0, stream>>>(
            hbuf, DIMM, in_w + (size_t)layer * XZ_DIM * DIMM, DIMM,
            in_b + layer * XZ_DIM, nullptr, xz, XZ_DIM, XZ_DIM, DIMM);

        conv_silu<<<(TT * DIN) / 256, 256, 0, stream>>>(
            xz, conv_w + layer * DIN * DCONV, conv_b + layer * DIN, xc);

        gemm_nt<<<dim3(1, TT / GBM), 256, 0, stream>>>(
            xc, DIN, xp_w + (size_t)layer * DBC_DIM * DIN, DIN,
            nullptr, nullptr, dbc, DBC_DIM, DBC_DIM, DIN);

        dt_kernel<<<(TT * DIN) / 256, 256, 0, stream>>>(
            dbc, dt_w + (size_t)layer * DIN * DTRANK, dt_b + layer * DIN, dtb);

        const float* Al = A_log + (size_t)layer * DIN * DSTATE;
        scan_phase1<<<BB * NC * 32, 256, 0, stream>>>(dtb, xc, dbc, Al, Pbuf, Hbuf);
        scan_phase2<<<(BB * DIN * DSTATE) / 256, 256, 0, stream>>>(Pbuf, Hbuf, Hin);
        scan_phase3<<<BB * NC * 32, 256, 0, stream>>>(dtb, xc, dbc, Al,
                                                      Dp + layer * DIN, Hin);

        g_kernel<<<(TT * DIN) / 256, 256, 0, stream>>>(xc, xz, dtb);

        gemm_nt<<<dim3(DIMM / GBN, TT / GBM), 256, 0, stream>>>(
            dtb, DIN, ow + (size_t)layer * DIMM * DIN, DIN,
            nullptr, xi, xo, DIMM, DIMM, DIN);
    }
}

// Round 3
// 1004.936 us; speedup vs baseline: 1.7293x; 1.2328x over previous
//
#include <hip/hip_runtime.h>
#include <math.h>

#define NB 4
#define DIMM 256
#define DSTATE 16
#define DCONV 4
#define DIN 512
#define DTRANK 16
#define BB 16
#define LL 512
#define TT (BB * LL)            // 8192 tokens
#define XZ_DIM (2 * DIN)        // 1024
#define DBC_DIM (DTRANK + 2 * DSTATE)  // 48
#define NC 4                    // scan chunks
#define CHUNK (LL / NC)         // 128

__device__ __forceinline__ unsigned short f2bf(float f) {
    union { float f; unsigned int u; } v; v.f = f;
    unsigned int r = v.u + 0x7fff + ((v.u >> 16) & 1);
    return (unsigned short)(r >> 16);
}

// ---------------- fp32 -> bf16 bulk convert (weights) ------------------------
__global__ __launch_bounds__(256) void cvt_kernel(const float* __restrict__ s,
                                                  unsigned short* __restrict__ d,
                                                  int n4) {
    int i = blockIdx.x * 256 + threadIdx.x;
    if (i < n4) {
        float4 v = ((const float4*)s)[i];
        ushort4 o;
        o.x = f2bf(v.x); o.y = f2bf(v.y); o.z = f2bf(v.z); o.w = f2bf(v.w);
        ((ushort4*)d)[i] = o;
    }
}

// ---------------- LayerNorm -> bf16 ------------------------------------------
__global__ __launch_bounds__(256) void ln_kernel(const float* __restrict__ x,
                                                 const float* __restrict__ w,
                                                 const float* __restrict__ bvec,
                                                 unsigned short* __restrict__ out) {
    int t = blockIdx.x;
    int i = threadIdx.x;
    float v = x[t * DIMM + i];
    float s = v, s2 = v * v;
#pragma unroll
    for (int off = 1; off < 64; off <<= 1) {
        s  += __shfl_xor(s, off);
        s2 += __shfl_xor(s2, off);
    }
    __shared__ float ss[4], ss2[4];
    int wid = i >> 6;
    if ((i & 63) == 0) { ss[wid] = s; ss2[wid] = s2; }
    __syncthreads();
    s  = ss[0] + ss[1] + ss[2] + ss[3];
    s2 = ss2[0] + ss2[1] + ss2[2] + ss2[3];
    float mu  = s * (1.0f / DIMM);
    float var = s2 * (1.0f / DIMM) - mu * mu;
    float r   = rsqrtf(var + 1e-5f);
    out[t * DIMM + i] = f2bf((v - mu) * r * w[i] + bvec[i]);
}

// ---------------- bf16 MFMA NT GEMM: C = A * Bw^T (+bias) (+resid) -----------
// A: M x K bf16 row-major; Bw: N x K bf16 row-major; C: M x N fp32.
// Block = 256 thr = 4 waves; tile 128(M) x 64(N) x 32(K); wave does 64x32.
#define TBM 128
#define TBN 64
#define TBK 32
#define LDK (TBK + 8)   // ushort row stride 40 (80 B)
__global__ __launch_bounds__(256) void gemm_bf16(const unsigned short* __restrict__ A, int lda,
                                                 const unsigned short* __restrict__ Bw, int ldb,
                                                 const float* __restrict__ bias,
                                                 const float* __restrict__ resid,
                                                 float* __restrict__ C, int ldc,
                                                 int N, int K) {
    using short8  = __attribute__((ext_vector_type(8))) short;
    using floatx4 = __attribute__((ext_vector_type(4))) float;
    __shared__ __align__(16) unsigned short As[TBM * LDK];
    __shared__ __align__(16) unsigned short Bs[TBN * LDK];

    int tid  = threadIdx.x;
    int m0   = blockIdx.y * TBM;
    int n0   = blockIdx.x * TBN;
    int w    = tid >> 6;
    int lane = tid & 63;
    int wm   = (w & 1) * 64;
    int wn   = (w >> 1) * 32;
    int lr   = lane & 15;
    int quad = lane >> 4;

    floatx4 acc[4][2] = {};

    int ar = tid >> 1;
    int ak = (tid & 1) * 16;
    int br = tid >> 2;
    int bk = (tid & 3) * 8;

    for (int k0 = 0; k0 < K; k0 += TBK) {
        {
            const unsigned short* src = &A[(size_t)(m0 + ar) * lda + k0 + ak];
            int4 a0 = *(const int4*)(src);
            int4 a1 = *(const int4*)(src + 8);
            *(int4*)&As[ar * LDK + ak]     = a0;
            *(int4*)&As[ar * LDK + ak + 8] = a1;
        }
        {
            int gn = n0 + br;
            int4 b0 = make_int4(0, 0, 0, 0);
            if (gn < N) b0 = *(const int4*)&Bw[(size_t)gn * ldb + k0 + bk];
            *(int4*)&Bs[br * LDK + bk] = b0;
        }
        __syncthreads();
        short8 af[4], bf[2];
#pragma unroll
        for (int i = 0; i < 4; ++i)
            af[i] = *(const short8*)&As[(wm + i * 16 + lr) * LDK + quad * 8];
#pragma unroll
        for (int j = 0; j < 2; ++j)
            bf[j] = *(const short8*)&Bs[(wn + j * 16 + lr) * LDK + quad * 8];
#pragma unroll
        for (int i = 0; i < 4; ++i)
#pragma unroll
            for (int j = 0; j < 2; ++j)
                acc[i][j] = __builtin_amdgcn_mfma_f32_16x16x32_bf16(af[i], bf[j], acc[i][j], 0, 0, 0);
        __syncthreads();
    }

#pragma unroll
    for (int j = 0; j < 2; ++j) {
        int cn = n0 + wn + j * 16 + lr;
        if (cn < N) {
            float bb = bias ? bias[cn] : 0.0f;
#pragma unroll
            for (int i = 0; i < 4; ++i) {
#pragma unroll
                for (int r = 0; r < 4; ++r) {
                    int cm = m0 + wm + i * 16 + quad * 4 + r;
                    float v = acc[i][j][r] + bb;
                    if (resid) v += resid[(size_t)cm * ldc + cn];
                    C[(size_t)cm * ldc + cn] = v;
                }
            }
        }
    }
}

// ---------------- fp32 tiled NT GEMM (kept for x_proj, N=48) -----------------
#define GBM 64
#define GBN 64
#define GBK 16
__global__ __launch_bounds__(256) void gemm_nt(const float* __restrict__ A, int lda,
                                               const float* __restrict__ Bw, int ldb,
                                               const float* __restrict__ bias,
                                               const float* __restrict__ resid,
                                               float* __restrict__ C, int ldc,
                                               int N, int K) {
    __shared__ float As[GBK][GBM + 4];
    __shared__ float Bs[GBK][GBN + 4];
    int tid = threadIdx.x;
    int tx = tid & 15;
    int ty = tid >> 4;
    int m0 = blockIdx.y * GBM;
    int n0 = blockIdx.x * GBN;
    int lrow = tid >> 2;
    int lcol = (tid & 3) * 4;

    float acc[4][4] = {};

    for (int k0 = 0; k0 < K; k0 += GBK) {
        {
            const float4 av = *(const float4*)&A[(size_t)(m0 + lrow) * lda + k0 + lcol];
            As[lcol + 0][lrow] = av.x;
            As[lcol + 1][lrow] = av.y;
            As[lcol + 2][lrow] = av.z;
            As[lcol + 3][lrow] = av.w;
        }
        {
            int gn = n0 + lrow;
            float4 bv = make_float4(0.f, 0.f, 0.f, 0.f);
            if (gn < N) bv = *(const float4*)&Bw[(size_t)gn * ldb + k0 + lcol];
            Bs[lcol + 0][lrow] = bv.x;
            Bs[lcol + 1][lrow] = bv.y;
            Bs[lcol + 2][lrow] = bv.z;
            Bs[lcol + 3][lrow] = bv.w;
        }
        __syncthreads();
#pragma unroll
        for (int kk = 0; kk < GBK; ++kk) {
            const float4 a = *(const float4*)&As[kk][ty * 4];
            const float4 b = *(const float4*)&Bs[kk][tx * 4];
            const float av[4] = {a.x, a.y, a.z, a.w};
            const float bv[4] = {b.x, b.y, b.z, b.w};
#pragma unroll
            for (int i = 0; i < 4; ++i)
#pragma unroll
                for (int j = 0; j < 4; ++j) acc[i][j] += av[i] * bv[j];
        }
        __syncthreads();
    }

    int n = n0 + tx * 4;
    if (n < N) {
        float4 bb = make_float4(0.f, 0.f, 0.f, 0.f);
        if (bias) bb = *(const float4*)&bias[n];
#pragma unroll
        for (int i = 0; i < 4; ++i) {
            int m = m0 + ty * 4 + i;
            float4 v = make_float4(acc[i][0] + bb.x, acc[i][1] + bb.y,
                                   acc[i][2] + bb.z, acc[i][3] + bb.w);
            if (resid) {
                const float4 rv = *(const float4*)&resid[(size_t)m * ldc + n];
                v.x += rv.x; v.y += rv.y; v.z += rv.z; v.w += rv.w;
            }
            *(float4*)&C[(size_t)m * ldc + n] = v;
        }
    }
}

// ---------------- Depthwise causal conv (4-tap) + SiLU -----------------------
__global__ __launch_bounds__(256) void conv_silu(const float* __restrict__ xz,
                                                 const float* __restrict__ cw,
                                                 const float* __restrict__ cb,
                                                 float* __restrict__ xc) {
    int idx = blockIdx.x * blockDim.x + threadIdx.x;
    int d = idx & (DIN - 1);
    int t = idx >> 9;
    int l = t & (LL - 1);
    int bq = t >> 9;
    float acc = cb[d];
#pragma unroll
    for (int k = 0; k < DCONV; ++k) {
        int ls = l - (DCONV - 1) + k;
        if (ls >= 0) acc += cw[d * DCONV + k] * xz[(size_t)(bq * LL + ls) * XZ_DIM + d];
    }
    xc[(size_t)t * DIN + d] = acc / (1.0f + __expf(-acc));
}

// ---------------- dt = softplus(dbc[:, :16] @ dtw^T + dtb) -------------------
__global__ __launch_bounds__(256) void dt_kernel(const float* __restrict__ dbc,
                                                 const float* __restrict__ dtw,
                                                 const float* __restrict__ dtbias,
                                                 float* __restrict__ dtout) {
    int idx = blockIdx.x * blockDim.x + threadIdx.x;
    int d = idx & (DIN - 1);
    int t = idx >> 9;
    float a = dtbias[d];
    const float4* wv = (const float4*)(dtw + d * DTRANK);
    const float* dr = dbc + (size_t)t * DBC_DIM;
#pragma unroll
    for (int q = 0; q < 4; ++q) {
        float4 w4 = wv[q];
        a += w4.x * dr[q * 4 + 0] + w4.y * dr[q * 4 + 1] +
             w4.z * dr[q * 4 + 2] + w4.w * dr[q * 4 + 3];
    }
    float sp = (a > 20.0f) ? a : log1pf(__expf(a));
    dtout[(size_t)t * DIN + d] = sp;
}

// ---------------- Selective scan, chunked (3 phases) -------------------------
__global__ __launch_bounds__(256) void scan_phase1(const float* __restrict__ dt,
                                                   const float* __restrict__ xc,
                                                   const float* __restrict__ dbc,
                                                   const float* __restrict__ A_log,
                                                   float* __restrict__ P,
                                                   float* __restrict__ H) {
    int bid = blockIdx.x;
    int dg = bid & 31;
    int c  = (bid >> 5) & (NC - 1);
    int b  = bid >> 7;
    int dl = threadIdx.x >> 4;
    int n  = threadIdx.x & 15;
    int d  = dg * 16 + dl;

    float a = -__expf(A_log[d * DSTATE + n]);
    float h = 0.0f, p = 1.0f;
    int t0 = c * CHUNK;
    for (int t = 0; t < CHUNK; ++t) {
        size_t row = (size_t)(b * LL + t0 + t);
        float dtv = dt[row * DIN + d];
        float u   = xc[row * DIN + d];
        float bt  = dbc[row * DBC_DIM + DTRANK + n];
        float dA  = __expf(dtv * a);
        h = dA * h + dtv * bt * u;
        p *= dA;
    }
    size_t idx = (((size_t)b * NC + c) * DIN + d) * DSTATE + n;
    P[idx] = p;
    H[idx] = h;
}

__global__ __launch_bounds__(256) void scan_phase2(const float* __restrict__ P,
                                                   const float* __restrict__ H,
                                                   float* __restrict__ Hin) {
    int idx = blockIdx.x * 256 + threadIdx.x;
    int b  = idx >> 13;
    int dn = idx & 8191;
    float h = 0.0f;
#pragma unroll
    for (int c = 0; c < NC; ++c) {
        size_t q = ((size_t)b * NC + c) * (DIN * DSTATE) + dn;
        Hin[q] = h;
        h = P[q] * h + H[q];
    }
}

__global__ __launch_bounds__(256) void scan_phase3(const float* __restrict__ dt,
                                                   float* __restrict__ xc,
                                                   const float* __restrict__ dbc,
                                                   const float* __restrict__ A_log,
                                                   const float* __restrict__ Dp,
                                                   const float* __restrict__ Hin) {
    int bid = blockIdx.x;
    int dg = bid & 31;
    int c  = (bid >> 5) & (NC - 1);
    int b  = bid >> 7;
    int dl = threadIdx.x >> 4;
    int n  = threadIdx.x & 15;
    int d  = dg * 16 + dl;

    float a  = -__expf(A_log[d * DSTATE + n]);
    float Dd = Dp[d];
    float h  = Hin[(((size_t)b * NC + c) * DIN + d) * DSTATE + n];
    int t0 = c * CHUNK;
    for (int t = 0; t < CHUNK; ++t) {
        size_t row = (size_t)(b * LL + t0 + t);
        float dtv = dt[row * DIN + d];
        float u   = xc[row * DIN + d];
        float bt  = dbc[row * DBC_DIM + DTRANK + n];
        float ct  = dbc[row * DBC_DIM + DTRANK + DSTATE + n];
        float dA  = __expf(dtv * a);
        h = dA * h + dtv * bt * u;
        float yp = h * ct;
        yp += __shfl_xor(yp, 1);
        yp += __shfl_xor(yp, 2);
        yp += __shfl_xor(yp, 4);
        yp += __shfl_xor(yp, 8);
        if (n == 0) xc[row * DIN + d] = yp + u * Dd;
    }
}

// ---------------- g = y * silu(z) -> bf16 -------------------------------------
__global__ __launch_bounds__(256) void g_kernel(const float* __restrict__ y,
                                                const float* __restrict__ xz,
                                                unsigned short* __restrict__ g) {
    int idx = blockIdx.x * blockDim.x + threadIdx.x;
    int d = idx & (DIN - 1);
    int t = idx >> 9;
    float zz = xz[(size_t)t * XZ_DIM + DIN + d];
    float yy = y[(size_t)t * DIN + d];
    g[idx] = f2bf(yy * (zz / (1.0f + __expf(-zz))));
}

extern "C" void kernel_launch(void* const* d_in, const int* in_sizes, int n_in,
                              void* d_out, int out_size, void* d_ws, size_t ws_size,
                              hipStream_t stream) {
    const float* x_in   = (const float*)d_in[0];
    const float* ln_w   = (const float*)d_in[1];
    const float* ln_b   = (const float*)d_in[2];
    const float* in_w   = (const float*)d_in[3];
    const float* in_b   = (const float*)d_in[4];
    const float* conv_w = (const float*)d_in[5];
    const float* conv_b = (const float*)d_in[6];
    const float* xp_w   = (const float*)d_in[7];
    const float* dt_w   = (const float*)d_in[8];
    const float* dt_b   = (const float*)d_in[9];
    const float* A_log  = (const float*)d_in[10];
    const float* Dp     = (const float*)d_in[11];
    const float* ow     = (const float*)d_in[12];
    float* out = (float*)d_out;

    float* ws   = (float*)d_ws;
    float* xbuf = ws;                         // TT*DIMM
    float* hbuf = xbuf + (size_t)TT * DIMM;   // TT*DIMM region (h_bf16, dbc, scan scratch)
    float* xz   = hbuf + (size_t)TT * DIMM;   // TT*1024
    float* xc   = xz   + (size_t)TT * XZ_DIM; // TT*DIN (u, then y in-place)
    float* dtb  = xc   + (size_t)TT * DIN;    // TT*DIN (dt fp32, then g bf16)
    float* dbc  = hbuf;                       // TT*48
    const size_t SCN = (size_t)BB * NC * DIN * DSTATE;   // 524288
    float* Pbuf  = hbuf + (size_t)TT * DBC_DIM;
    float* Hbuf  = Pbuf + SCN;
    float* Hin   = Hbuf + SCN;
    unsigned short* hb   = (unsigned short*)hbuf;        // h bf16 (dead before dbc written)
    unsigned short* gb   = (unsigned short*)dtb;         // g bf16 (over dead dt)
    // bf16 weights appended after previous 80 MB
    unsigned short* wbf  = (unsigned short*)(ws + (size_t)20971520);
    unsigned short* inwb = wbf;                              // 4 * 1024 * 256
    unsigned short* owb  = wbf + (size_t)NB * XZ_DIM * DIMM; // 4 * 256 * 512

    // convert weights (every launch; same work each call)
    cvt_kernel<<<(NB * XZ_DIM * DIMM / 4 + 255) / 256, 256, 0, stream>>>(
        in_w, inwb, NB * XZ_DIM * DIMM / 4);
    cvt_kernel<<<(NB * DIMM * DIN / 4 + 255) / 256, 256, 0, stream>>>(
        ow, owb, NB * DIMM * DIN / 4);

    for (int layer = 0; layer < NB; ++layer) {
        const float* xi = (layer == 0) ? x_in : xbuf;
        float* xo = (layer == NB - 1) ? out : xbuf;

        ln_kernel<<<TT, 256, 0, stream>>>(xi, ln_w + layer * DIMM, ln_b + layer * DIMM, hb);

        // in_proj: (TT x 256) @ (1024 x 256)^T + b -> xz, bf16 MFMA
        gemm_bf16<<<dim3(XZ_DIM / TBN, TT / TBM), 256, 0, stream>>>(
            hb, DIMM, inwb + (size_t)layer * XZ_DIM * DIMM, DIMM,
            in_b + layer * XZ_DIM, nullptr, xz, XZ_DIM, XZ_DIM, DIMM);

        conv_silu<<<(TT * DIN) / 256, 256, 0, stream>>>(
            xz, conv_w + layer * DIN * DCONV, conv_b + layer * DIN, xc);

        gemm_nt<<<dim3(1, TT / GBM), 256, 0, stream>>>(
            xc, DIN, xp_w + (size_t)layer * DBC_DIM * DIN, DIN,
            nullptr, nullptr, dbc, DBC_DIM, DBC_DIM, DIN);

        dt_kernel<<<(TT * DIN) / 256, 256, 0, stream>>>(
            dbc, dt_w + (size_t)layer * DIN * DTRANK, dt_b + layer * DIN, dtb);

        const float* Al = A_log + (size_t)layer * DIN * DSTATE;
        scan_phase1<<<BB * NC * 32, 256, 0, stream>>>(dtb, xc, dbc, Al, Pbuf, Hbuf);
        scan_phase2<<<(BB * DIN * DSTATE) / 256, 256, 0, stream>>>(Pbuf, Hbuf, Hin);
        scan_phase3<<<BB * NC * 32, 256, 0, stream>>>(dtb, xc, dbc, Al,
                                                      Dp + layer * DIN, Hin);

        g_kernel<<<(TT * DIN) / 256, 256, 0, stream>>>(xc, xz, gb);

        // out_proj: (TT x 512) @ (256 x 512)^T + x -> xo, bf16 MFMA
        gemm_bf16<<<dim3(DIMM / TBN, TT / TBM), 256, 0, stream>>>(
            gb, DIN, owb + (size_t)layer * DIMM * DIN, DIN,
            nullptr, xi, xo, DIMM, DIMM, DIN);
    }
}

// Round 4
// 863.943 us; speedup vs baseline: 2.0115x; 1.1632x over previous
//
#include <hip/hip_runtime.h>
#include <math.h>

#define NB 4
#define DIMM 256
#define DSTATE 16
#define DCONV 4
#define DIN 512
#define DTRANK 16
#define BB 16
#define LL 512
#define TT (BB * LL)            // 8192 tokens
#define XZ_DIM (2 * DIN)        // 1024
#define DBC_DIM (DTRANK + 2 * DSTATE)  // 48
#define NC 16                   // scan chunks
#define CHUNK (LL / NC)         // 32

__device__ __forceinline__ unsigned short f2bf(float f) {
    union { float f; unsigned int u; } v; v.f = f;
    unsigned int r = v.u + 0x7fff + ((v.u >> 16) & 1);
    return (unsigned short)(r >> 16);
}

// ---------------- fp32 -> bf16 bulk convert (weights) ------------------------
__global__ __launch_bounds__(256) void cvt_kernel(const float* __restrict__ s,
                                                  unsigned short* __restrict__ d,
                                                  int n4) {
    int i = blockIdx.x * 256 + threadIdx.x;
    if (i < n4) {
        float4 v = ((const float4*)s)[i];
        ushort4 o;
        o.x = f2bf(v.x); o.y = f2bf(v.y); o.z = f2bf(v.z); o.w = f2bf(v.w);
        ((ushort4*)d)[i] = o;
    }
}

// ---------------- LayerNorm -> bf16 ------------------------------------------
__global__ __launch_bounds__(256) void ln_kernel(const float* __restrict__ x,
                                                 const float* __restrict__ w,
                                                 const float* __restrict__ bvec,
                                                 unsigned short* __restrict__ out) {
    int t = blockIdx.x;
    int i = threadIdx.x;
    float v = x[t * DIMM + i];
    float s = v, s2 = v * v;
#pragma unroll
    for (int off = 1; off < 64; off <<= 1) {
        s  += __shfl_xor(s, off);
        s2 += __shfl_xor(s2, off);
    }
    __shared__ float ss[4], ss2[4];
    int wid = i >> 6;
    if ((i & 63) == 0) { ss[wid] = s; ss2[wid] = s2; }
    __syncthreads();
    s  = ss[0] + ss[1] + ss[2] + ss[3];
    s2 = ss2[0] + ss2[1] + ss2[2] + ss2[3];
    float mu  = s * (1.0f / DIMM);
    float var = s2 * (1.0f / DIMM) - mu * mu;
    float r   = rsqrtf(var + 1e-5f);
    out[t * DIMM + i] = f2bf((v - mu) * r * w[i] + bvec[i]);
}

// ---------------- bf16 MFMA NT GEMM: C = A * Bw^T (+bias) (+resid) -----------
// Optional column split: cols >= nsplit go to C2 (same ldc).
#define TBM 128
#define TBN 64
#define TBK 32
#define LDK (TBK + 8)
__global__ __launch_bounds__(256) void gemm_bf16(const unsigned short* __restrict__ A, int lda,
                                                 const unsigned short* __restrict__ Bw, int ldb,
                                                 const float* __restrict__ bias,
                                                 const float* __restrict__ resid,
                                                 float* __restrict__ C,
                                                 float* __restrict__ C2, int nsplit,
                                                 int ldc, int N, int K) {
    using short8  = __attribute__((ext_vector_type(8))) short;
    using floatx4 = __attribute__((ext_vector_type(4))) float;
    __shared__ __align__(16) unsigned short As[TBM * LDK];
    __shared__ __align__(16) unsigned short Bs[TBN * LDK];

    int tid  = threadIdx.x;
    int m0   = blockIdx.y * TBM;
    int n0   = blockIdx.x * TBN;
    int w    = tid >> 6;
    int lane = tid & 63;
    int wm   = (w & 1) * 64;
    int wn   = (w >> 1) * 32;
    int lr   = lane & 15;
    int quad = lane >> 4;

    floatx4 acc[4][2] = {};

    int ar = tid >> 1;
    int ak = (tid & 1) * 16;
    int br = tid >> 2;
    int bk = (tid & 3) * 8;

    for (int k0 = 0; k0 < K; k0 += TBK) {
        {
            const unsigned short* src = &A[(size_t)(m0 + ar) * lda + k0 + ak];
            int4 a0 = *(const int4*)(src);
            int4 a1 = *(const int4*)(src + 8);
            *(int4*)&As[ar * LDK + ak]     = a0;
            *(int4*)&As[ar * LDK + ak + 8] = a1;
        }
        {
            int gn = n0 + br;
            int4 b0 = make_int4(0, 0, 0, 0);
            if (gn < N) b0 = *(const int4*)&Bw[(size_t)gn * ldb + k0 + bk];
            *(int4*)&Bs[br * LDK + bk] = b0;
        }
        __syncthreads();
        short8 af[4], bf[2];
#pragma unroll
        for (int i = 0; i < 4; ++i)
            af[i] = *(const short8*)&As[(wm + i * 16 + lr) * LDK + quad * 8];
#pragma unroll
        for (int j = 0; j < 2; ++j)
            bf[j] = *(const short8*)&Bs[(wn + j * 16 + lr) * LDK + quad * 8];
#pragma unroll
        for (int i = 0; i < 4; ++i)
#pragma unroll
            for (int j = 0; j < 2; ++j)
                acc[i][j] = __builtin_amdgcn_mfma_f32_16x16x32_bf16(af[i], bf[j], acc[i][j], 0, 0, 0);
        __syncthreads();
    }

#pragma unroll
    for (int j = 0; j < 2; ++j) {
        int cn = n0 + wn + j * 16 + lr;
        if (cn < N) {
            float bb = bias ? bias[cn] : 0.0f;
            float* dst = C;
            int col = cn;
            if (C2 && cn >= nsplit) { dst = C2; col = cn - nsplit; }
#pragma unroll
            for (int i = 0; i < 4; ++i) {
#pragma unroll
                for (int r = 0; r < 4; ++r) {
                    int cm = m0 + wm + i * 16 + quad * 4 + r;
                    float v = acc[i][j][r] + bb;
                    if (resid) v += resid[(size_t)cm * ldc + col];
                    dst[(size_t)cm * ldc + col] = v;
                }
            }
        }
    }
}

// ---------------- fp32 tiled NT GEMM (x_proj, N=48) --------------------------
#define GBM 64
#define GBN 64
#define GBK 16
__global__ __launch_bounds__(256) void gemm_nt(const float* __restrict__ A, int lda,
                                               const float* __restrict__ Bw, int ldb,
                                               const float* __restrict__ bias,
                                               const float* __restrict__ resid,
                                               float* __restrict__ C, int ldc,
                                               int N, int K) {
    __shared__ float As[GBK][GBM + 4];
    __shared__ float Bs[GBK][GBN + 4];
    int tid = threadIdx.x;
    int tx = tid & 15;
    int ty = tid >> 4;
    int m0 = blockIdx.y * GBM;
    int n0 = blockIdx.x * GBN;
    int lrow = tid >> 2;
    int lcol = (tid & 3) * 4;

    float acc[4][4] = {};

    for (int k0 = 0; k0 < K; k0 += GBK) {
        {
            const float4 av = *(const float4*)&A[(size_t)(m0 + lrow) * lda + k0 + lcol];
            As[lcol + 0][lrow] = av.x;
            As[lcol + 1][lrow] = av.y;
            As[lcol + 2][lrow] = av.z;
            As[lcol + 3][lrow] = av.w;
        }
        {
            int gn = n0 + lrow;
            float4 bv = make_float4(0.f, 0.f, 0.f, 0.f);
            if (gn < N) bv = *(const float4*)&Bw[(size_t)gn * ldb + k0 + lcol];
            Bs[lcol + 0][lrow] = bv.x;
            Bs[lcol + 1][lrow] = bv.y;
            Bs[lcol + 2][lrow] = bv.z;
            Bs[lcol + 3][lrow] = bv.w;
        }
        __syncthreads();
#pragma unroll
        for (int kk = 0; kk < GBK; ++kk) {
            const float4 a = *(const float4*)&As[kk][ty * 4];
            const float4 b = *(const float4*)&Bs[kk][tx * 4];
            const float av[4] = {a.x, a.y, a.z, a.w};
            const float bv[4] = {b.x, b.y, b.z, b.w};
#pragma unroll
            for (int i = 0; i < 4; ++i)
#pragma unroll
                for (int j = 0; j < 4; ++j) acc[i][j] += av[i] * bv[j];
        }
        __syncthreads();
    }

    int n = n0 + tx * 4;
    if (n < N) {
        float4 bb = make_float4(0.f, 0.f, 0.f, 0.f);
        if (bias) bb = *(const float4*)&bias[n];
#pragma unroll
        for (int i = 0; i < 4; ++i) {
            int m = m0 + ty * 4 + i;
            float4 v = make_float4(acc[i][0] + bb.x, acc[i][1] + bb.y,
                                   acc[i][2] + bb.z, acc[i][3] + bb.w);
            if (resid) {
                const float4 rv = *(const float4*)&resid[(size_t)m * ldc + n];
                v.x += rv.x; v.y += rv.y; v.z += rv.z; v.w += rv.w;
            }
            *(float4*)&C[(size_t)m * ldc + n] = v;
        }
    }
}

// ---------------- Depthwise causal conv (4-tap) + SiLU (X separate buffer) ---
__global__ __launch_bounds__(256) void conv_silu(const float* __restrict__ xin,
                                                 const float* __restrict__ cw,
                                                 const float* __restrict__ cb,
                                                 float* __restrict__ xc) {
    int idx = blockIdx.x * blockDim.x + threadIdx.x;
    int d = idx & (DIN - 1);
    int t = idx >> 9;
    int l = t & (LL - 1);
    int bq = t >> 9;
    float acc = cb[d];
#pragma unroll
    for (int k = 0; k < DCONV; ++k) {
        int ls = l - (DCONV - 1) + k;
        if (ls >= 0) acc += cw[d * DCONV + k] * xin[(size_t)(bq * LL + ls) * DIN + d];
    }
    xc[(size_t)t * DIN + d] = acc / (1.0f + __expf(-acc));
}

// ---------------- dt = softplus(dbc[:, :16] @ dtw^T + dtb) -------------------
__global__ __launch_bounds__(256) void dt_kernel(const float* __restrict__ dbc,
                                                 const float* __restrict__ dtw,
                                                 const float* __restrict__ dtbias,
                                                 float* __restrict__ dtout) {
    int idx = blockIdx.x * blockDim.x + threadIdx.x;
    int d = idx & (DIN - 1);
    int t = idx >> 9;
    float a = dtbias[d];
    const float4* wv = (const float4*)(dtw + d * DTRANK);
    const float* dr = dbc + (size_t)t * DBC_DIM;
#pragma unroll
    for (int q = 0; q < 4; ++q) {
        float4 w4 = wv[q];
        a += w4.x * dr[q * 4 + 0] + w4.y * dr[q * 4 + 1] +
             w4.z * dr[q * 4 + 2] + w4.w * dr[q * 4 + 3];
    }
    float sp = (a > 20.0f) ? a : log1pf(__expf(a));
    dtout[(size_t)t * DIN + d] = sp;
}

// ---------------- Selective scan: register-state, 3 phases -------------------
// Thread = (b, chunk, d) holding h[0..16) in registers.
// Phase1: local scan from h=0 over CHUNK steps; store S=sum(dt) and final h.
// H layout: [b][c][n][d] (coalesced across d); S: [b][c][d].
__global__ __launch_bounds__(256) void scan_p1(const float* __restrict__ dt,
                                               const float* __restrict__ xc,
                                               const float* __restrict__ dbc,
                                               const float* __restrict__ A_log,
                                               float* __restrict__ S,
                                               float* __restrict__ H) {
    int bid = blockIdx.x;
    int dh = bid & 1;
    int c  = (bid >> 1) & (NC - 1);
    int b  = bid >> 5;
    int d  = dh * 256 + threadIdx.x;
    int base = b * LL + c * CHUNK;

    __shared__ float LB[CHUNK * 16];
    if (threadIdx.x < 128) {
        int s = threadIdx.x >> 2, j = threadIdx.x & 3;
        *(float4*)&LB[s * 16 + j * 4] =
            *(const float4*)&dbc[(size_t)(base + s) * DBC_DIM + DTRANK + j * 4];
    }
    float a[16];
    {
        const float4* ar = (const float4*)(A_log + d * DSTATE);
#pragma unroll
        for (int q = 0; q < 4; ++q) {
            float4 v = ar[q];
            a[q * 4 + 0] = -__expf(v.x); a[q * 4 + 1] = -__expf(v.y);
            a[q * 4 + 2] = -__expf(v.z); a[q * 4 + 3] = -__expf(v.w);
        }
    }
    __syncthreads();

    float h[16];
#pragma unroll
    for (int n = 0; n < 16; ++n) h[n] = 0.0f;
    float Ssum = 0.0f;
    float dtv = dt[(size_t)base * DIN + d];
    float u   = xc[(size_t)base * DIN + d];
#pragma unroll 4
    for (int s = 0; s < CHUNK; ++s) {
        // prefetch next step (1 row past end is still valid ws memory)
        float ndt = dt[(size_t)(base + s + 1) * DIN + d];
        float nu  = xc[(size_t)(base + s + 1) * DIN + d];
        float wv = dtv * u;
        Ssum += dtv;
#pragma unroll
        for (int q = 0; q < 4; ++q) {
            float4 bt = *(const float4*)&LB[s * 16 + q * 4];
            const float btr[4] = {bt.x, bt.y, bt.z, bt.w};
#pragma unroll
            for (int r = 0; r < 4; ++r) {
                int n = q * 4 + r;
                float dA = __expf(dtv * a[n]);
                h[n] = dA * h[n] + wv * btr[r];
            }
        }
        dtv = ndt; u = nu;
    }
    size_t sc = (size_t)b * NC + c;
    S[sc * DIN + d] = Ssum;
#pragma unroll
    for (int n = 0; n < 16; ++n) H[(sc * 16 + n) * DIN + d] = h[n];
}

// Phase2: per (b,d): combine chunks serially; Hin overwrites H in place.
__global__ __launch_bounds__(256) void scan_p2(const float* __restrict__ A_log,
                                               const float* __restrict__ S,
                                               float* __restrict__ H) {
    int idx = blockIdx.x * 256 + threadIdx.x;   // BB*DIN
    int d = idx & (DIN - 1);
    int b = idx >> 9;
    float a[16];
    {
        const float4* ar = (const float4*)(A_log + d * DSTATE);
#pragma unroll
        for (int q = 0; q < 4; ++q) {
            float4 v = ar[q];
            a[q * 4 + 0] = -__expf(v.x); a[q * 4 + 1] = -__expf(v.y);
            a[q * 4 + 2] = -__expf(v.z); a[q * 4 + 3] = -__expf(v.w);
        }
    }
    float h[16];
#pragma unroll
    for (int n = 0; n < 16; ++n) h[n] = 0.0f;
    for (int c = 0; c < NC; ++c) {
        size_t sc = (size_t)b * NC + c;
        float Sv = S[sc * DIN + d];
#pragma unroll
        for (int n = 0; n < 16; ++n) {
            float P = __expf(a[n] * Sv);
            size_t q = (sc * 16 + n) * DIN + d;
            float Hc = H[q];
            H[q] = h[n];                 // carry-in for this chunk
            h[n] = P * h[n] + Hc;
        }
    }
}

// Phase3: full scan per chunk with h0 = Hin (in H buf), y in-place over xc.
__global__ __launch_bounds__(256) void scan_p3(const float* __restrict__ dt,
                                               float* __restrict__ xc,
                                               const float* __restrict__ dbc,
                                               const float* __restrict__ A_log,
                                               const float* __restrict__ Dp,
                                               const float* __restrict__ Hin) {
    int bid = blockIdx.x;
    int dh = bid & 1;
    int c  = (bid >> 1) & (NC - 1);
    int b  = bid >> 5;
    int d  = dh * 256 + threadIdx.x;
    int base = b * LL + c * CHUNK;

    __shared__ float LB[CHUNK * 32];
    {
        int s = threadIdx.x >> 3, j = threadIdx.x & 7;
        *(float4*)&LB[s * 32 + j * 4] =
            *(const float4*)&dbc[(size_t)(base + s) * DBC_DIM + DTRANK + j * 4];
    }
    float a[16];
    {
        const float4* ar = (const float4*)(A_log + d * DSTATE);
#pragma unroll
        for (int q = 0; q < 4; ++q) {
            float4 v = ar[q];
            a[q * 4 + 0] = -__expf(v.x); a[q * 4 + 1] = -__expf(v.y);
            a[q * 4 + 2] = -__expf(v.z); a[q * 4 + 3] = -__expf(v.w);
        }
    }
    float Dd = Dp[d];
    float h[16];
    size_t sc = (size_t)b * NC + c;
#pragma unroll
    for (int n = 0; n < 16; ++n) h[n] = Hin[(sc * 16 + n) * DIN + d];
    __syncthreads();

    float dtv = dt[(size_t)base * DIN + d];
    float u   = xc[(size_t)base * DIN + d];
#pragma unroll 4
    for (int s = 0; s < CHUNK; ++s) {
        float ndt = dt[(size_t)(base + s + 1) * DIN + d];
        float nu  = xc[(size_t)(base + s + 1) * DIN + d];
        float wv = dtv * u;
        float y  = u * Dd;
#pragma unroll
        for (int q = 0; q < 4; ++q) {
            float4 bt = *(const float4*)&LB[s * 32 + q * 4];
            float4 ct = *(const float4*)&LB[s * 32 + 16 + q * 4];
            const float btr[4] = {bt.x, bt.y, bt.z, bt.w};
            const float ctr[4] = {ct.x, ct.y, ct.z, ct.w};
#pragma unroll
            for (int r = 0; r < 4; ++r) {
                int n = q * 4 + r;
                float dA = __expf(dtv * a[n]);
                h[n] = dA * h[n] + wv * btr[r];
                y += h[n] * ctr[r];
            }
        }
        xc[(size_t)(base + s) * DIN + d] = y;
        dtv = ndt; u = nu;
    }
}

// ---------------- g = y * silu(z) -> bf16 ------------------------------------
__global__ __launch_bounds__(256) void g_kernel(const float* __restrict__ y,
                                                const float* __restrict__ z,
                                                unsigned short* __restrict__ g) {
    int idx = blockIdx.x * blockDim.x + threadIdx.x;
    float zz = z[idx];
    float yy = y[idx];
    g[idx] = f2bf(yy * (zz / (1.0f + __expf(-zz))));
}

extern "C" void kernel_launch(void* const* d_in, const int* in_sizes, int n_in,
                              void* d_out, int out_size, void* d_ws, size_t ws_size,
                              hipStream_t stream) {
    const float* x_in   = (const float*)d_in[0];
    const float* ln_w   = (const float*)d_in[1];
    const float* ln_b   = (const float*)d_in[2];
    const float* in_w   = (const float*)d_in[3];
    const float* in_b   = (const float*)d_in[4];
    const float* conv_w = (const float*)d_in[5];
    const float* conv_b = (const float*)d_in[6];
    const float* xp_w   = (const float*)d_in[7];
    const float* dt_w   = (const float*)d_in[8];
    const float* dt_b   = (const float*)d_in[9];
    const float* A_log  = (const float*)d_in[10];
    const float* Dp     = (const float*)d_in[11];
    const float* ow     = (const float*)d_in[12];
    float* out = (float*)d_out;

    const size_t M = 1048576;
    float* ws   = (float*)d_ws;
    float* xbuf = ws;                     // 2M floats: layer in/out
    float* hbuf = xbuf + 2 * M;           // 2M: h bf16, then dbc
    float* Xbuf = hbuf + 2 * M;           // 4M: x-part, then scan scratch H+S
    float* Zbuf = Xbuf + 4 * M;           // 4M: z-part
    float* xc   = Zbuf + 4 * M;           // 4M: u, then y in-place
    float* dtb  = xc   + 4 * M;           // 4M: dt fp32, then g bf16
    float* dbc  = hbuf;                   // TT*48
    unsigned short* hb = (unsigned short*)hbuf;   // bf16 h (dead before dbc)
    unsigned short* gb = (unsigned short*)dtb;    // bf16 g (over dead dt)
    float* Hbuf = Xbuf;                   // BB*NC*16*DIN = 2M floats
    float* Sbuf = Xbuf + 2 * M;           // BB*NC*DIN = 128K floats
    unsigned short* wbf  = (unsigned short*)(ws + 20 * M);
    unsigned short* inwb = wbf;                              // 4*1024*256
    unsigned short* owb  = wbf + (size_t)NB * XZ_DIM * DIMM; // 4*256*512

    cvt_kernel<<<(NB * XZ_DIM * DIMM / 4 + 255) / 256, 256, 0, stream>>>(
        in_w, inwb, NB * XZ_DIM * DIMM / 4);
    cvt_kernel<<<(NB * DIMM * DIN / 4 + 255) / 256, 256, 0, stream>>>(
        ow, owb, NB * DIMM * DIN / 4);

    for (int layer = 0; layer < NB; ++layer) {
        const float* xi = (layer == 0) ? x_in : xbuf;
        float* xo = (layer == NB - 1) ? out : xbuf;

        ln_kernel<<<TT, 256, 0, stream>>>(xi, ln_w + layer * DIMM, ln_b + layer * DIMM, hb);

        // in_proj -> split X / Z buffers (both TT x 512)
        gemm_bf16<<<dim3(XZ_DIM / TBN, TT / TBM), 256, 0, stream>>>(
            hb, DIMM, inwb + (size_t)layer * XZ_DIM * DIMM, DIMM,
            in_b + layer * XZ_DIM, nullptr, Xbuf, Zbuf, DIN, DIN, XZ_DIM, DIMM);

        conv_silu<<<(TT * DIN) / 256, 256, 0, stream>>>(
            Xbuf, conv_w + layer * DIN * DCONV, conv_b + layer * DIN, xc);

        gemm_nt<<<dim3(1, TT / GBM), 256, 0, stream>>>(
            xc, DIN, xp_w + (size_t)layer * DBC_DIM * DIN, DIN,
            nullptr, nullptr, dbc, DBC_DIM, DBC_DIM, DIN);

        dt_kernel<<<(TT * DIN) / 256, 256, 0, stream>>>(
            dbc, dt_w + (size_t)layer * DIN * DTRANK, dt_b + layer * DIN, dtb);

        const float* Al = A_log + (size_t)layer * DIN * DSTATE;
        scan_p1<<<BB * NC * 2, 256, 0, stream>>>(dtb, xc, dbc, Al, Sbuf, Hbuf);
        scan_p2<<<(BB * DIN) / 256, 256, 0, stream>>>(Al, Sbuf, Hbuf);
        scan_p3<<<BB * NC * 2, 256, 0, stream>>>(dtb, xc, dbc, Al,
                                                 Dp + layer * DIN, Hbuf);

        g_kernel<<<(TT * DIN) / 256, 256, 0, stream>>>(xc, Zbuf, gb);

        gemm_bf16<<<dim3(DIMM / TBN, TT / TBM), 256, 0, stream>>>(
            gb, DIN, owb + (size_t)layer * DIMM * DIN, DIN,
            nullptr, xi, xo, nullptr, 1 << 30, DIMM, DIMM, DIN);
    }
}

// Round 5
// 749.524 us; speedup vs baseline: 2.3185x; 1.1527x over previous
//
#include <hip/hip_runtime.h>
#include <math.h>

#define NB 4
#define DIMM 256
#define DSTATE 16
#define DCONV 4
#define DIN 512
#define DTRANK 16
#define BB 16
#define LL 512
#define TT (BB * LL)            // 8192 tokens
#define XZ_DIM (2 * DIN)        // 1024
#define DBC_DIM (DTRANK + 2 * DSTATE)  // 48
#define NC 16                   // scan chunks
#define CHUNK (LL / NC)         // 32

__device__ __forceinline__ unsigned short f2bf(float f) {
    union { float f; unsigned int u; } v; v.f = f;
    unsigned int r = v.u + 0x7fff + ((v.u >> 16) & 1);
    return (unsigned short)(r >> 16);
}
__device__ __forceinline__ float bf2f(unsigned short u) {
    union { unsigned int i; float f; } v; v.i = ((unsigned int)u) << 16;
    return v.f;
}

// ---------------- fp32 -> bf16 bulk convert (weights) ------------------------
__global__ __launch_bounds__(256) void cvt_kernel(const float* __restrict__ s,
                                                  unsigned short* __restrict__ d,
                                                  int n4) {
    int i = blockIdx.x * 256 + threadIdx.x;
    if (i < n4) {
        float4 v = ((const float4*)s)[i];
        ushort4 o;
        o.x = f2bf(v.x); o.y = f2bf(v.y); o.z = f2bf(v.z); o.w = f2bf(v.w);
        ((ushort4*)d)[i] = o;
    }
}

// ---------------- LayerNorm -> bf16 ------------------------------------------
__global__ __launch_bounds__(256) void ln_kernel(const float* __restrict__ x,
                                                 const float* __restrict__ w,
                                                 const float* __restrict__ bvec,
                                                 unsigned short* __restrict__ out) {
    int t = blockIdx.x;
    int i = threadIdx.x;
    float v = x[t * DIMM + i];
    float s = v, s2 = v * v;
#pragma unroll
    for (int off = 1; off < 64; off <<= 1) {
        s  += __shfl_xor(s, off);
        s2 += __shfl_xor(s2, off);
    }
    __shared__ float ss[4], ss2[4];
    int wid = i >> 6;
    if ((i & 63) == 0) { ss[wid] = s; ss2[wid] = s2; }
    __syncthreads();
    s  = ss[0] + ss[1] + ss[2] + ss[3];
    s2 = ss2[0] + ss2[1] + ss2[2] + ss2[3];
    float mu  = s * (1.0f / DIMM);
    float var = s2 * (1.0f / DIMM) - mu * mu;
    float r   = rsqrtf(var + 1e-5f);
    out[t * DIMM + i] = f2bf((v - mu) * r * w[i] + bvec[i]);
}

// ---------------- bf16 MFMA NT GEMM: C = A * Bw^T (+bias) (+resid) -----------
// Columns >= nsplit go to C2b as bf16 (same ldc). C is fp32.
#define TBM 128
#define TBN 64
#define TBK 32
#define LDK (TBK + 8)
__global__ __launch_bounds__(256) void gemm_bf16(const unsigned short* __restrict__ A, int lda,
                                                 const unsigned short* __restrict__ Bw, int ldb,
                                                 const float* __restrict__ bias,
                                                 const float* __restrict__ resid,
                                                 float* __restrict__ C,
                                                 unsigned short* __restrict__ C2b, int nsplit,
                                                 int ldc, int N, int K) {
    using short8  = __attribute__((ext_vector_type(8))) short;
    using floatx4 = __attribute__((ext_vector_type(4))) float;
    __shared__ __align__(16) unsigned short As[TBM * LDK];
    __shared__ __align__(16) unsigned short Bs[TBN * LDK];

    int tid  = threadIdx.x;
    int m0   = blockIdx.y * TBM;
    int n0   = blockIdx.x * TBN;
    int w    = tid >> 6;
    int lane = tid & 63;
    int wm   = (w & 1) * 64;
    int wn   = (w >> 1) * 32;
    int lr   = lane & 15;
    int quad = lane >> 4;

    floatx4 acc[4][2] = {};

    int ar = tid >> 1;
    int ak = (tid & 1) * 16;
    int br = tid >> 2;
    int bk = (tid & 3) * 8;

    for (int k0 = 0; k0 < K; k0 += TBK) {
        {
            const unsigned short* src = &A[(size_t)(m0 + ar) * lda + k0 + ak];
            int4 a0 = *(const int4*)(src);
            int4 a1 = *(const int4*)(src + 8);
            *(int4*)&As[ar * LDK + ak]     = a0;
            *(int4*)&As[ar * LDK + ak + 8] = a1;
        }
        {
            int gn = n0 + br;
            int4 b0 = make_int4(0, 0, 0, 0);
            if (gn < N) b0 = *(const int4*)&Bw[(size_t)gn * ldb + k0 + bk];
            *(int4*)&Bs[br * LDK + bk] = b0;
        }
        __syncthreads();
        short8 af[4], bf[2];
#pragma unroll
        for (int i = 0; i < 4; ++i)
            af[i] = *(const short8*)&As[(wm + i * 16 + lr) * LDK + quad * 8];
#pragma unroll
        for (int j = 0; j < 2; ++j)
            bf[j] = *(const short8*)&Bs[(wn + j * 16 + lr) * LDK + quad * 8];
#pragma unroll
        for (int i = 0; i < 4; ++i)
#pragma unroll
            for (int j = 0; j < 2; ++j)
                acc[i][j] = __builtin_amdgcn_mfma_f32_16x16x32_bf16(af[i], bf[j], acc[i][j], 0, 0, 0);
        __syncthreads();
    }

#pragma unroll
    for (int j = 0; j < 2; ++j) {
        int cn = n0 + wn + j * 16 + lr;
        if (cn < N) {
            float bb = bias ? bias[cn] : 0.0f;
            if (C2b && cn >= nsplit) {
                int col = cn - nsplit;
#pragma unroll
                for (int i = 0; i < 4; ++i)
#pragma unroll
                    for (int r = 0; r < 4; ++r) {
                        int cm = m0 + wm + i * 16 + quad * 4 + r;
                        C2b[(size_t)cm * ldc + col] = f2bf(acc[i][j][r] + bb);
                    }
            } else {
#pragma unroll
                for (int i = 0; i < 4; ++i)
#pragma unroll
                    for (int r = 0; r < 4; ++r) {
                        int cm = m0 + wm + i * 16 + quad * 4 + r;
                        float v = acc[i][j][r] + bb;
                        if (resid) v += resid[(size_t)cm * ldc + cn];
                        C[(size_t)cm * ldc + cn] = v;
                    }
            }
        }
    }
}

// ---------------- Depthwise causal conv (4-tap) + SiLU -----------------------
// Writes fp32 xc (for scan) and bf16 xcb (for x_proj MFMA).
__global__ __launch_bounds__(256) void conv_silu(const float* __restrict__ xin,
                                                 const float* __restrict__ cw,
                                                 const float* __restrict__ cb,
                                                 float* __restrict__ xc,
                                                 unsigned short* __restrict__ xcb) {
    int idx = blockIdx.x * blockDim.x + threadIdx.x;
    int d = idx & (DIN - 1);
    int t = idx >> 9;
    int l = t & (LL - 1);
    int bq = t >> 9;
    float acc = cb[d];
#pragma unroll
    for (int k = 0; k < DCONV; ++k) {
        int ls = l - (DCONV - 1) + k;
        if (ls >= 0) acc += cw[d * DCONV + k] * xin[(size_t)(bq * LL + ls) * DIN + d];
    }
    float v = acc / (1.0f + __expf(-acc));
    xc[(size_t)t * DIN + d] = v;
    xcb[(size_t)t * DIN + d] = f2bf(v);
}

// ---------------- Selective scan: register-state, dt fused, 3 phases ---------
// Thread = (b, chunk, d) holding h[0..16) in registers.
// dt recomputed in-kernel: softplus(dbc[t,:16] . dtw[d] + dtb[d]).
__global__ __launch_bounds__(256) void scan_p1(const float* __restrict__ xc,
                                               const float* __restrict__ dbc,
                                               const float* __restrict__ A_log,
                                               const float* __restrict__ dtw,
                                               const float* __restrict__ dtbias,
                                               float* __restrict__ S,
                                               float* __restrict__ H) {
    int bid = blockIdx.x;
    int dh = bid & 1;
    int c  = (bid >> 1) & (NC - 1);
    int b  = bid >> 5;
    int d  = dh * 256 + threadIdx.x;
    int base = b * LL + c * CHUNK;

    __shared__ float LB[CHUNK * DBC_DIM];
    for (int i = threadIdx.x; i < CHUNK * DBC_DIM / 4; i += 256)
        ((float4*)LB)[i] = ((const float4*)(dbc + (size_t)base * DBC_DIM))[i];

    float a[16], wv16[16];
    {
        const float4* ar = (const float4*)(A_log + d * DSTATE);
        const float4* wr = (const float4*)(dtw + d * DTRANK);
#pragma unroll
        for (int q = 0; q < 4; ++q) {
            float4 v = ar[q];
            a[q * 4 + 0] = -__expf(v.x); a[q * 4 + 1] = -__expf(v.y);
            a[q * 4 + 2] = -__expf(v.z); a[q * 4 + 3] = -__expf(v.w);
            float4 ww = wr[q];
            wv16[q * 4 + 0] = ww.x; wv16[q * 4 + 1] = ww.y;
            wv16[q * 4 + 2] = ww.z; wv16[q * 4 + 3] = ww.w;
        }
    }
    float db = dtbias[d];
    __syncthreads();

    float h[16];
#pragma unroll
    for (int n = 0; n < 16; ++n) h[n] = 0.0f;
    float Ssum = 0.0f;
    float u = xc[(size_t)base * DIN + d];
#pragma unroll 4
    for (int s = 0; s < CHUNK; ++s) {
        float nu = xc[(size_t)(base + s + 1) * DIN + d];
        const float* row = &LB[s * DBC_DIM];
        float dot = db;
#pragma unroll
        for (int k = 0; k < 16; ++k) dot += row[k] * wv16[k];
        float dtv = (dot > 20.0f) ? dot : log1pf(__expf(dot));
        float wv = dtv * u;
        Ssum += dtv;
#pragma unroll
        for (int q = 0; q < 4; ++q) {
            float4 bt = *(const float4*)&row[DTRANK + q * 4];
            const float btr[4] = {bt.x, bt.y, bt.z, bt.w};
#pragma unroll
            for (int r = 0; r < 4; ++r) {
                int n = q * 4 + r;
                float dA = __expf(dtv * a[n]);
                h[n] = dA * h[n] + wv * btr[r];
            }
        }
        u = nu;
    }
    size_t sc = (size_t)b * NC + c;
    S[sc * DIN + d] = Ssum;
#pragma unroll
    for (int n = 0; n < 16; ++n) H[(sc * 16 + n) * DIN + d] = h[n];
}

// Phase2: per (b,d): combine chunks serially; Hin overwrites H in place.
__global__ __launch_bounds__(256) void scan_p2(const float* __restrict__ A_log,
                                               const float* __restrict__ S,
                                               float* __restrict__ H) {
    int idx = blockIdx.x * 256 + threadIdx.x;   // BB*DIN
    int d = idx & (DIN - 1);
    int b = idx >> 9;
    float a[16];
    {
        const float4* ar = (const float4*)(A_log + d * DSTATE);
#pragma unroll
        for (int q = 0; q < 4; ++q) {
            float4 v = ar[q];
            a[q * 4 + 0] = -__expf(v.x); a[q * 4 + 1] = -__expf(v.y);
            a[q * 4 + 2] = -__expf(v.z); a[q * 4 + 3] = -__expf(v.w);
        }
    }
    float h[16];
#pragma unroll
    for (int n = 0; n < 16; ++n) h[n] = 0.0f;
    for (int c = 0; c < NC; ++c) {
        size_t sc = (size_t)b * NC + c;
        float Sv = S[sc * DIN + d];
#pragma unroll
        for (int n = 0; n < 16; ++n) {
            float P = __expf(a[n] * Sv);
            size_t q = (sc * 16 + n) * DIN + d;
            float Hc = H[q];
            H[q] = h[n];
            h[n] = P * h[n] + Hc;
        }
    }
}

// Phase3: scan per chunk with h0 = Hin; fused y = scan-out + u*D and
// g = y * silu(z) written directly as bf16.
__global__ __launch_bounds__(256) void scan_p3(const float* __restrict__ xc,
                                               const unsigned short* __restrict__ Zb,
                                               const float* __restrict__ dbc,
                                               const float* __restrict__ A_log,
                                               const float* __restrict__ dtw,
                                               const float* __restrict__ dtbias,
                                               const float* __restrict__ Dp,
                                               const float* __restrict__ Hin,
                                               unsigned short* __restrict__ gb) {
    int bid = blockIdx.x;
    int dh = bid & 1;
    int c  = (bid >> 1) & (NC - 1);
    int b  = bid >> 5;
    int d  = dh * 256 + threadIdx.x;
    int base = b * LL + c * CHUNK;

    __shared__ float LB[CHUNK * DBC_DIM];
    for (int i = threadIdx.x; i < CHUNK * DBC_DIM / 4; i += 256)
        ((float4*)LB)[i] = ((const float4*)(dbc + (size_t)base * DBC_DIM))[i];

    float a[16], wv16[16];
    {
        const float4* ar = (const float4*)(A_log + d * DSTATE);
        const float4* wr = (const float4*)(dtw + d * DTRANK);
#pragma unroll
        for (int q = 0; q < 4; ++q) {
            float4 v = ar[q];
            a[q * 4 + 0] = -__expf(v.x); a[q * 4 + 1] = -__expf(v.y);
            a[q * 4 + 2] = -__expf(v.z); a[q * 4 + 3] = -__expf(v.w);
            float4 ww = wr[q];
            wv16[q * 4 + 0] = ww.x; wv16[q * 4 + 1] = ww.y;
            wv16[q * 4 + 2] = ww.z; wv16[q * 4 + 3] = ww.w;
        }
    }
    float db = dtbias[d];
    float Dd = Dp[d];
    float h[16];
    size_t sc = (size_t)b * NC + c;
#pragma unroll
    for (int n = 0; n < 16; ++n) h[n] = Hin[(sc * 16 + n) * DIN + d];
    __syncthreads();

    float u = xc[(size_t)base * DIN + d];
#pragma unroll 4
    for (int s = 0; s < CHUNK; ++s) {
        float nu = xc[(size_t)(base + s + 1) * DIN + d];
        unsigned short zu = Zb[(size_t)(base + s) * DIN + d];
        const float* row = &LB[s * DBC_DIM];
        float dot = db;
#pragma unroll
        for (int k = 0; k < 16; ++k) dot += row[k] * wv16[k];
        float dtv = (dot > 20.0f) ? dot : log1pf(__expf(dot));
        float wv = dtv * u;
        float y  = u * Dd;
#pragma unroll
        for (int q = 0; q < 4; ++q) {
            float4 bt = *(const float4*)&row[DTRANK + q * 4];
            float4 ct = *(const float4*)&row[DTRANK + DSTATE + q * 4];
            const float btr[4] = {bt.x, bt.y, bt.z, bt.w};
            const float ctr[4] = {ct.x, ct.y, ct.z, ct.w};
#pragma unroll
            for (int r = 0; r < 4; ++r) {
                int n = q * 4 + r;
                float dA = __expf(dtv * a[n]);
                h[n] = dA * h[n] + wv * btr[r];
                y += h[n] * ctr[r];
            }
        }
        float zf = bf2f(zu);
        float g = y * (zf / (1.0f + __expf(-zf)));
        gb[(size_t)(base + s) * DIN + d] = f2bf(g);
        u = nu;
    }
}

extern "C" void kernel_launch(void* const* d_in, const int* in_sizes, int n_in,
                              void* d_out, int out_size, void* d_ws, size_t ws_size,
                              hipStream_t stream) {
    const float* x_in   = (const float*)d_in[0];
    const float* ln_w   = (const float*)d_in[1];
    const float* ln_b   = (const float*)d_in[2];
    const float* in_w   = (const float*)d_in[3];
    const float* in_b   = (const float*)d_in[4];
    const float* conv_w = (const float*)d_in[5];
    const float* conv_b = (const float*)d_in[6];
    const float* xp_w   = (const float*)d_in[7];
    const float* dt_w   = (const float*)d_in[8];
    const float* dt_b   = (const float*)d_in[9];
    const float* A_log  = (const float*)d_in[10];
    const float* Dp     = (const float*)d_in[11];
    const float* ow     = (const float*)d_in[12];
    float* out = (float*)d_out;

    const size_t M = 1048576;
    float* ws   = (float*)d_ws;
    float* xbuf = ws;                     // 2M floats: layer in/out
    float* hbuf = xbuf + 2 * M;           // 2M: h bf16, then dbc
    float* Xbuf = hbuf + 2 * M;           // 4M: X fp32, then scan H+S
    float* Zregion = Xbuf + 4 * M;        // 4M region: Zb bf16 (2M used)
    float* xc   = Zregion + 4 * M;        // 4M: u fp32
    float* dtb  = xc   + 4 * M;           // 4M region: gb bf16 (2M) + xcb bf16 (2M)
    float* dbc  = hbuf;                   // TT*48
    unsigned short* hb  = (unsigned short*)hbuf;        // bf16 h (dead before dbc)
    unsigned short* Zb  = (unsigned short*)Zregion;     // bf16 z
    unsigned short* gb  = (unsigned short*)dtb;         // bf16 g
    unsigned short* xcb = (unsigned short*)(dtb + 2 * M); // bf16 conv out
    float* Hbuf = Xbuf;                   // BB*NC*16*DIN = 2M floats
    float* Sbuf = Xbuf + 2 * M;           // BB*NC*DIN = 128K floats
    unsigned short* wbf  = (unsigned short*)(ws + 20 * M);
    unsigned short* inwb = wbf;                              // 4*1024*256
    unsigned short* owb  = inwb + (size_t)NB * XZ_DIM * DIMM; // 4*256*512
    unsigned short* xpwb = owb + (size_t)NB * DIMM * DIN;     // 4*48*512

    cvt_kernel<<<(NB * XZ_DIM * DIMM / 4 + 255) / 256, 256, 0, stream>>>(
        in_w, inwb, NB * XZ_DIM * DIMM / 4);
    cvt_kernel<<<(NB * DIMM * DIN / 4 + 255) / 256, 256, 0, stream>>>(
        ow, owb, NB * DIMM * DIN / 4);
    cvt_kernel<<<(NB * DBC_DIM * DIN / 4 + 255) / 256, 256, 0, stream>>>(
        xp_w, xpwb, NB * DBC_DIM * DIN / 4);

    for (int layer = 0; layer < NB; ++layer) {
        const float* xi = (layer == 0) ? x_in : xbuf;
        float* xo = (layer == NB - 1) ? out : xbuf;

        ln_kernel<<<TT, 256, 0, stream>>>(xi, ln_w + layer * DIMM, ln_b + layer * DIMM, hb);

        // in_proj: X half -> fp32 Xbuf, Z half -> bf16 Zb
        gemm_bf16<<<dim3(XZ_DIM / TBN, TT / TBM), 256, 0, stream>>>(
            hb, DIMM, inwb + (size_t)layer * XZ_DIM * DIMM, DIMM,
            in_b + layer * XZ_DIM, nullptr, Xbuf, Zb, DIN, DIN, XZ_DIM, DIMM);

        conv_silu<<<(TT * DIN) / 256, 256, 0, stream>>>(
            Xbuf, conv_w + layer * DIN * DCONV, conv_b + layer * DIN, xc, xcb);

        // x_proj: (TT x 512)bf16 @ (48 x 512)^T bf16 -> dbc fp32
        gemm_bf16<<<dim3(1, TT / TBM), 256, 0, stream>>>(
            xcb, DIN, xpwb + (size_t)layer * DBC_DIM * DIN, DIN,
            nullptr, nullptr, dbc, nullptr, 1 << 30, DBC_DIM, DBC_DIM, DIN);

        const float* Al  = A_log + (size_t)layer * DIN * DSTATE;
        const float* dwl = dt_w + (size_t)layer * DIN * DTRANK;
        const float* dbl = dt_b + layer * DIN;
        scan_p1<<<BB * NC * 2, 256, 0, stream>>>(xc, dbc, Al, dwl, dbl, Sbuf, Hbuf);
        scan_p2<<<(BB * DIN) / 256, 256, 0, stream>>>(Al, Sbuf, Hbuf);
        scan_p3<<<BB * NC * 2, 256, 0, stream>>>(xc, Zb, dbc, Al, dwl, dbl,
                                                 Dp + layer * DIN, Hbuf, gb);

        // out_proj: (TT x 512)bf16 @ (256 x 512)^T + x -> xo
        gemm_bf16<<<dim3(DIMM / TBN, TT / TBM), 256, 0, stream>>>(
            gb, DIN, owb + (size_t)layer * DIMM * DIN, DIN,
            nullptr, xi, xo, nullptr, 1 << 30, DIMM, DIMM, DIN);
    }
}

// Round 6
// 714.369 us; speedup vs baseline: 2.4326x; 1.0492x over previous
//
#include <hip/hip_runtime.h>
#include <math.h>

#define NB 4
#define DIMM 256
#define DSTATE 16
#define DCONV 4
#define DIN 512
#define DTRANK 16
#define BB 16
#define LL 512
#define TT (BB * LL)            // 8192 tokens
#define XZ_DIM (2 * DIN)        // 1024
#define DBC_DIM (DTRANK + 2 * DSTATE)  // 48
#define NC 16                   // scan chunks
#define CHUNK (LL / NC)         // 32

__device__ __forceinline__ unsigned short f2bf(float f) {
    union { float f; unsigned int u; } v; v.f = f;
    unsigned int r = v.u + 0x7fff + ((v.u >> 16) & 1);
    return (unsigned short)(r >> 16);
}
__device__ __forceinline__ float bf2f(unsigned short u) {
    union { unsigned int i; float f; } v; v.i = ((unsigned int)u) << 16;
    return v.f;
}

// ---------------- fp32 -> bf16 weight convert (all three, one dispatch) ------
__global__ __launch_bounds__(256) void cvt3_kernel(const float* __restrict__ s1,
                                                   unsigned short* __restrict__ d1, int n1,
                                                   const float* __restrict__ s2,
                                                   unsigned short* __restrict__ d2, int n2,
                                                   const float* __restrict__ s3,
                                                   unsigned short* __restrict__ d3, int n3) {
    int stride = gridDim.x * 256;
    for (int i = blockIdx.x * 256 + threadIdx.x; i < n1; i += stride) {
        float4 v = ((const float4*)s1)[i];
        ushort4 o; o.x = f2bf(v.x); o.y = f2bf(v.y); o.z = f2bf(v.z); o.w = f2bf(v.w);
        ((ushort4*)d1)[i] = o;
    }
    for (int i = blockIdx.x * 256 + threadIdx.x; i < n2; i += stride) {
        float4 v = ((const float4*)s2)[i];
        ushort4 o; o.x = f2bf(v.x); o.y = f2bf(v.y); o.z = f2bf(v.z); o.w = f2bf(v.w);
        ((ushort4*)d2)[i] = o;
    }
    for (int i = blockIdx.x * 256 + threadIdx.x; i < n3; i += stride) {
        float4 v = ((const float4*)s3)[i];
        ushort4 o; o.x = f2bf(v.x); o.y = f2bf(v.y); o.z = f2bf(v.z); o.w = f2bf(v.w);
        ((ushort4*)d3)[i] = o;
    }
}

// ---------------- LayerNorm -> bf16 ------------------------------------------
__global__ __launch_bounds__(256) void ln_kernel(const float* __restrict__ x,
                                                 const float* __restrict__ w,
                                                 const float* __restrict__ bvec,
                                                 unsigned short* __restrict__ out) {
    int t = blockIdx.x;
    int i = threadIdx.x;
    float v = x[t * DIMM + i];
    float s = v, s2 = v * v;
#pragma unroll
    for (int off = 1; off < 64; off <<= 1) {
        s  += __shfl_xor(s, off);
        s2 += __shfl_xor(s2, off);
    }
    __shared__ float ss[4], ss2[4];
    int wid = i >> 6;
    if ((i & 63) == 0) { ss[wid] = s; ss2[wid] = s2; }
    __syncthreads();
    s  = ss[0] + ss[1] + ss[2] + ss[3];
    s2 = ss2[0] + ss2[1] + ss2[2] + ss2[3];
    float mu  = s * (1.0f / DIMM);
    float var = s2 * (1.0f / DIMM) - mu * mu;
    float r   = rsqrtf(var + 1e-5f);
    out[t * DIMM + i] = f2bf((v - mu) * r * w[i] + bvec[i]);
}

// ---------------- bf16 MFMA NT GEMM ------------------------------------------
// Mode A (C1b != null): bf16 outputs, cols < nsplit -> C1b, else C2b (ldc each).
// Mode B (C1b == null): fp32 C (+resid).
#define TBM 128
#define TBN 64
#define TBK 32
#define LDKW (TBK + 8)
__global__ __launch_bounds__(256) void gemm_bf16(const unsigned short* __restrict__ A, int lda,
                                                 const unsigned short* __restrict__ Bw, int ldb,
                                                 const float* __restrict__ bias,
                                                 const float* __restrict__ resid,
                                                 float* __restrict__ C,
                                                 unsigned short* __restrict__ C1b,
                                                 unsigned short* __restrict__ C2b, int nsplit,
                                                 int ldc, int N, int K) {
    using short8  = __attribute__((ext_vector_type(8))) short;
    using floatx4 = __attribute__((ext_vector_type(4))) float;
    __shared__ __align__(16) unsigned short As[TBM * LDKW];
    __shared__ __align__(16) unsigned short Bs[TBN * LDKW];

    int tid  = threadIdx.x;
    int m0   = blockIdx.y * TBM;
    int n0   = blockIdx.x * TBN;
    int w    = tid >> 6;
    int lane = tid & 63;
    int wm   = (w & 1) * 64;
    int wn   = (w >> 1) * 32;
    int lr   = lane & 15;
    int quad = lane >> 4;

    floatx4 acc[4][2] = {};

    int ar = tid >> 1;
    int ak = (tid & 1) * 16;
    int br = tid >> 2;
    int bk = (tid & 3) * 8;

    for (int k0 = 0; k0 < K; k0 += TBK) {
        {
            const unsigned short* src = &A[(size_t)(m0 + ar) * lda + k0 + ak];
            int4 a0 = *(const int4*)(src);
            int4 a1 = *(const int4*)(src + 8);
            *(int4*)&As[ar * LDKW + ak]     = a0;
            *(int4*)&As[ar * LDKW + ak + 8] = a1;
        }
        {
            int gn = n0 + br;
            int4 b0 = make_int4(0, 0, 0, 0);
            if (gn < N) b0 = *(const int4*)&Bw[(size_t)gn * ldb + k0 + bk];
            *(int4*)&Bs[br * LDKW + bk] = b0;
        }
        __syncthreads();
        short8 af[4], bf[2];
#pragma unroll
        for (int i = 0; i < 4; ++i)
            af[i] = *(const short8*)&As[(wm + i * 16 + lr) * LDKW + quad * 8];
#pragma unroll
        for (int j = 0; j < 2; ++j)
            bf[j] = *(const short8*)&Bs[(wn + j * 16 + lr) * LDKW + quad * 8];
#pragma unroll
        for (int i = 0; i < 4; ++i)
#pragma unroll
            for (int j = 0; j < 2; ++j)
                acc[i][j] = __builtin_amdgcn_mfma_f32_16x16x32_bf16(af[i], bf[j], acc[i][j], 0, 0, 0);
        __syncthreads();
    }

#pragma unroll
    for (int j = 0; j < 2; ++j) {
        int cn = n0 + wn + j * 16 + lr;
        if (cn < N) {
            float bb = bias ? bias[cn] : 0.0f;
            if (C1b) {
                unsigned short* dst = (cn < nsplit) ? C1b : C2b;
                int col = (cn < nsplit) ? cn : cn - nsplit;
#pragma unroll
                for (int i = 0; i < 4; ++i)
#pragma unroll
                    for (int r = 0; r < 4; ++r) {
                        int cm = m0 + wm + i * 16 + quad * 4 + r;
                        dst[(size_t)cm * ldc + col] = f2bf(acc[i][j][r] + bb);
                    }
            } else {
#pragma unroll
                for (int i = 0; i < 4; ++i)
#pragma unroll
                    for (int r = 0; r < 4; ++r) {
                        int cm = m0 + wm + i * 16 + quad * 4 + r;
                        float v = acc[i][j][r] + bb;
                        if (resid) v += resid[(size_t)cm * ldc + cn];
                        C[(size_t)cm * ldc + cn] = v;
                    }
            }
        }
    }
}

// ---------------- Depthwise causal conv (4-tap) + SiLU, bf16 in/out ----------
__global__ __launch_bounds__(256) void conv_silu(const unsigned short* __restrict__ Xb,
                                                 const float* __restrict__ cw,
                                                 const float* __restrict__ cb,
                                                 unsigned short* __restrict__ xcb) {
    int idx = blockIdx.x * blockDim.x + threadIdx.x;
    int d = idx & (DIN - 1);
    int t = idx >> 9;
    int l = t & (LL - 1);
    int bq = t >> 9;
    float acc = cb[d];
#pragma unroll
    for (int k = 0; k < DCONV; ++k) {
        int ls = l - (DCONV - 1) + k;
        if (ls >= 0) acc += cw[d * DCONV + k] * bf2f(Xb[(size_t)(bq * LL + ls) * DIN + d]);
    }
    float v = acc / (1.0f + __expf(-acc));
    xcb[(size_t)t * DIN + d] = f2bf(v);
}

// ---------------- Selective scan: state-split (2 thr/d, 8 states each) -------
// grid = BB*NC*4 blocks; block covers 128 d x 2 state-halves.
// H layout: [sc][d][16] (contiguous per (d)). dt computed here, stored bf16.
__global__ __launch_bounds__(256) void scan_p1(const unsigned short* __restrict__ xcb,
                                               const float* __restrict__ dbc,
                                               const float* __restrict__ A_log,
                                               const float* __restrict__ dtw,
                                               const float* __restrict__ dtbias,
                                               unsigned short* __restrict__ dtb,
                                               float* __restrict__ S,
                                               float* __restrict__ H) {
    int bid = blockIdx.x;
    int dq = bid & 3;
    int c  = (bid >> 2) & (NC - 1);
    int b  = bid >> 6;
    int dloc = threadIdx.x >> 1;
    int sh   = threadIdx.x & 1;
    int d  = dq * 128 + dloc;
    int n0 = sh * 8;
    int base = b * LL + c * CHUNK;

    __shared__ float LB[CHUNK * DBC_DIM];
    for (int i = threadIdx.x; i < CHUNK * DBC_DIM / 4; i += 256)
        ((float4*)LB)[i] = ((const float4*)(dbc + (size_t)base * DBC_DIM))[i];

    float a[8], wv16[16];
    {
        const float4* ar = (const float4*)(A_log + d * DSTATE + n0);
        float4 v0 = ar[0], v1 = ar[1];
        a[0] = -__expf(v0.x); a[1] = -__expf(v0.y); a[2] = -__expf(v0.z); a[3] = -__expf(v0.w);
        a[4] = -__expf(v1.x); a[5] = -__expf(v1.y); a[6] = -__expf(v1.z); a[7] = -__expf(v1.w);
        const float4* wr = (const float4*)(dtw + d * DTRANK);
#pragma unroll
        for (int q = 0; q < 4; ++q) {
            float4 ww = wr[q];
            wv16[q * 4 + 0] = ww.x; wv16[q * 4 + 1] = ww.y;
            wv16[q * 4 + 2] = ww.z; wv16[q * 4 + 3] = ww.w;
        }
    }
    float db = dtbias[d];
    __syncthreads();

    float h[8];
#pragma unroll
    for (int j = 0; j < 8; ++j) h[j] = 0.0f;
    float Ssum = 0.0f;
    float u = bf2f(xcb[(size_t)base * DIN + d]);
#pragma unroll 4
    for (int s = 0; s < CHUNK; ++s) {
        float nu = bf2f(xcb[(size_t)(base + s + 1) * DIN + d]);
        const float* row = &LB[s * DBC_DIM];
        float dot = db;
#pragma unroll
        for (int k = 0; k < 16; ++k) dot += row[k] * wv16[k];
        float dtv = (dot > 20.0f) ? dot : log1pf(__expf(dot));
        if (sh == 0) dtb[(size_t)(base + s) * DIN + d] = f2bf(dtv);
        Ssum += dtv;
        float wv = dtv * u;
#pragma unroll
        for (int j = 0; j < 8; ++j) {
            float dA = __expf(dtv * a[j]);
            h[j] = dA * h[j] + wv * row[DTRANK + n0 + j];
        }
        u = nu;
    }
    size_t sc = (size_t)b * NC + c;
    if (sh == 0) S[sc * DIN + d] = Ssum;
#pragma unroll
    for (int j = 0; j < 8; ++j) H[(sc * DIN + d) * 16 + n0 + j] = h[j];
}

// Phase2: thread per (b,d,n); serial over chunks; Hin overwrites H in place.
__global__ __launch_bounds__(256) void scan_p2(const float* __restrict__ A_log,
                                               const float* __restrict__ S,
                                               float* __restrict__ H) {
    int idx = blockIdx.x * 256 + threadIdx.x;   // BB*DIN*16
    int n = idx & 15;
    int d = (idx >> 4) & (DIN - 1);
    int b = idx >> 13;
    float a = -__expf(A_log[d * DSTATE + n]);
    float h = 0.0f;
#pragma unroll
    for (int c = 0; c < NC; ++c) {
        size_t sc = (size_t)b * NC + c;
        float Sv = S[sc * DIN + d];
        size_t q = (sc * DIN + d) * 16 + n;
        float Hc = H[q];
        H[q] = h;
        h = __expf(a * Sv) * h + Hc;
    }
}

// Phase3: state-split scan; reads dt bf16; fused y + g = y*silu(z) -> bf16.
__global__ __launch_bounds__(256) void scan_p3(const unsigned short* __restrict__ xcb,
                                               const unsigned short* __restrict__ dtb,
                                               const unsigned short* __restrict__ Zb,
                                               const float* __restrict__ dbc,
                                               const float* __restrict__ A_log,
                                               const float* __restrict__ Dp,
                                               const float* __restrict__ Hin,
                                               unsigned short* __restrict__ gb) {
    int bid = blockIdx.x;
    int dq = bid & 3;
    int c  = (bid >> 2) & (NC - 1);
    int b  = bid >> 6;
    int dloc = threadIdx.x >> 1;
    int sh   = threadIdx.x & 1;
    int d  = dq * 128 + dloc;
    int n0 = sh * 8;
    int base = b * LL + c * CHUNK;

    __shared__ float LB[CHUNK * DBC_DIM];
    for (int i = threadIdx.x; i < CHUNK * DBC_DIM / 4; i += 256)
        ((float4*)LB)[i] = ((const float4*)(dbc + (size_t)base * DBC_DIM))[i];

    float a[8];
    {
        const float4* ar = (const float4*)(A_log + d * DSTATE + n0);
        float4 v0 = ar[0], v1 = ar[1];
        a[0] = -__expf(v0.x); a[1] = -__expf(v0.y); a[2] = -__expf(v0.z); a[3] = -__expf(v0.w);
        a[4] = -__expf(v1.x); a[5] = -__expf(v1.y); a[6] = -__expf(v1.z); a[7] = -__expf(v1.w);
    }
    float Dd = Dp[d];
    size_t sc = (size_t)b * NC + c;
    float h[8];
#pragma unroll
    for (int j = 0; j < 8; ++j) h[j] = Hin[(sc * DIN + d) * 16 + n0 + j];
    __syncthreads();

    float u   = bf2f(xcb[(size_t)base * DIN + d]);
    float dtv = bf2f(dtb[(size_t)base * DIN + d]);
#pragma unroll 4
    for (int s = 0; s < CHUNK; ++s) {
        float nu  = bf2f(xcb[(size_t)(base + s + 1) * DIN + d]);
        float ndt = bf2f(dtb[(size_t)(base + s + 1) * DIN + d]);
        const float* row = &LB[s * DBC_DIM];
        float wv = dtv * u;
        float y  = (sh == 0) ? u * Dd : 0.0f;
#pragma unroll
        for (int j = 0; j < 8; ++j) {
            float dA = __expf(dtv * a[j]);
            h[j] = dA * h[j] + wv * row[DTRANK + n0 + j];
            y += h[j] * row[DTRANK + DSTATE + n0 + j];
        }
        y += __shfl_xor(y, 1);
        if (sh == 0) {
            float zf = bf2f(Zb[(size_t)(base + s) * DIN + d]);
            float g = y * (zf / (1.0f + __expf(-zf)));
            gb[(size_t)(base + s) * DIN + d] = f2bf(g);
        }
        u = nu; dtv = ndt;
    }
}

extern "C" void kernel_launch(void* const* d_in, const int* in_sizes, int n_in,
                              void* d_out, int out_size, void* d_ws, size_t ws_size,
                              hipStream_t stream) {
    const float* x_in   = (const float*)d_in[0];
    const float* ln_w   = (const float*)d_in[1];
    const float* ln_b   = (const float*)d_in[2];
    const float* in_w   = (const float*)d_in[3];
    const float* in_b   = (const float*)d_in[4];
    const float* conv_w = (const float*)d_in[5];
    const float* conv_b = (const float*)d_in[6];
    const float* xp_w   = (const float*)d_in[7];
    const float* dt_w   = (const float*)d_in[8];
    const float* dt_b   = (const float*)d_in[9];
    const float* A_log  = (const float*)d_in[10];
    const float* Dp     = (const float*)d_in[11];
    const float* ow     = (const float*)d_in[12];
    float* out = (float*)d_out;

    const size_t M = 1048576;
    float* ws = (float*)d_ws;
    float* xbuf = ws;                              // [0,2M) fp32 layer io
    unsigned short* hb  = (unsigned short*)(ws + 2 * M);   // [2M,3M) bf16 TT*256
    float* dbc = ws + 3 * M;                       // [3M,3.5M) fp32 TT*48
    unsigned short* Xb  = (unsigned short*)(ws + 4 * M);   // [4M,6M) bf16 TT*512
    unsigned short* Zb  = (unsigned short*)(ws + 6 * M);   // [6M,8M)
    unsigned short* xcb = (unsigned short*)(ws + 8 * M);   // [8M,10M)
    unsigned short* dtb = (unsigned short*)(ws + 10 * M);  // [10M,12M)
    unsigned short* gb  = (unsigned short*)(ws + 12 * M);  // [12M,14M)
    float* Hbuf = ws + 14 * M;                     // [14M,16M) BB*NC*DIN*16
    float* Sbuf = ws + 16 * M;                     // [16M,16.125M)
    unsigned short* inwb = (unsigned short*)(ws + 17 * M);           // 4*1024*256
    unsigned short* owb  = inwb + (size_t)NB * XZ_DIM * DIMM;
    unsigned short* xpwb = owb + (size_t)NB * DIMM * DIN;

    cvt3_kernel<<<256, 256, 0, stream>>>(
        in_w, inwb, NB * XZ_DIM * DIMM / 4,
        ow,   owb,  NB * DIMM * DIN / 4,
        xp_w, xpwb, NB * DBC_DIM * DIN / 4);

    for (int layer = 0; layer < NB; ++layer) {
        const float* xi = (layer == 0) ? x_in : xbuf;
        float* xo = (layer == NB - 1) ? out : xbuf;

        ln_kernel<<<TT, 256, 0, stream>>>(xi, ln_w + layer * DIMM, ln_b + layer * DIMM, hb);

        // in_proj: both halves bf16 (X -> Xb, Z -> Zb)
        gemm_bf16<<<dim3(XZ_DIM / TBN, TT / TBM), 256, 0, stream>>>(
            hb, DIMM, inwb + (size_t)layer * XZ_DIM * DIMM, DIMM,
            in_b + layer * XZ_DIM, nullptr, nullptr, Xb, Zb, DIN, DIN, XZ_DIM, DIMM);

        conv_silu<<<(TT * DIN) / 256, 256, 0, stream>>>(
            Xb, conv_w + layer * DIN * DCONV, conv_b + layer * DIN, xcb);

        // x_proj: bf16 MFMA -> dbc fp32
        gemm_bf16<<<dim3(1, TT / TBM), 256, 0, stream>>>(
            xcb, DIN, xpwb + (size_t)layer * DBC_DIM * DIN, DIN,
            nullptr, nullptr, dbc, nullptr, nullptr, 0, DBC_DIM, DBC_DIM, DIN);

        const float* Al  = A_log + (size_t)layer * DIN * DSTATE;
        const float* dwl = dt_w + (size_t)layer * DIN * DTRANK;
        const float* dbl = dt_b + layer * DIN;
        scan_p1<<<BB * NC * 4, 256, 0, stream>>>(xcb, dbc, Al, dwl, dbl, dtb, Sbuf, Hbuf);
        scan_p2<<<(BB * DIN * 16) / 256, 256, 0, stream>>>(Al, Sbuf, Hbuf);
        scan_p3<<<BB * NC * 4, 256, 0, stream>>>(xcb, dtb, Zb, dbc, Al,
                                                 Dp + layer * DIN, Hbuf, gb);

        // out_proj: fp32 out + residual
        gemm_bf16<<<dim3(DIMM / TBN, TT / TBM), 256, 0, stream>>>(
            gb, DIN, owb + (size_t)layer * DIMM * DIN, DIN,
            nullptr, xi, xo, nullptr, nullptr, 0, DIMM, DIMM, DIN);
    }
}

// Round 7
// 688.934 us; speedup vs baseline: 2.5224x; 1.0369x over previous
//
#include <hip/hip_runtime.h>
#include <math.h>

#define NB 4
#define DIMM 256
#define DSTATE 16
#define DCONV 4
#define DIN 512
#define DTRANK 16
#define BB 16
#define LL 512
#define TT (BB * LL)            // 8192 tokens
#define XZ_DIM (2 * DIN)        // 1024
#define DBC_DIM (DTRANK + 2 * DSTATE)  // 48
#define NC 32                   // scan chunks
#define CHUNK (LL / NC)         // 16

__device__ __forceinline__ unsigned short f2bf(float f) {
    union { float f; unsigned int u; } v; v.f = f;
    unsigned int r = v.u + 0x7fff + ((v.u >> 16) & 1);
    return (unsigned short)(r >> 16);
}
__device__ __forceinline__ float bf2f(unsigned short u) {
    union { unsigned int i; float f; } v; v.i = ((unsigned int)u) << 16;
    return v.f;
}

// ---------------- fp32 -> bf16 weight convert (all three, one dispatch) ------
__global__ __launch_bounds__(256) void cvt3_kernel(const float* __restrict__ s1,
                                                   unsigned short* __restrict__ d1, int n1,
                                                   const float* __restrict__ s2,
                                                   unsigned short* __restrict__ d2, int n2,
                                                   const float* __restrict__ s3,
                                                   unsigned short* __restrict__ d3, int n3) {
    int stride = gridDim.x * 256;
    for (int i = blockIdx.x * 256 + threadIdx.x; i < n1; i += stride) {
        float4 v = ((const float4*)s1)[i];
        ushort4 o; o.x = f2bf(v.x); o.y = f2bf(v.y); o.z = f2bf(v.z); o.w = f2bf(v.w);
        ((ushort4*)d1)[i] = o;
    }
    for (int i = blockIdx.x * 256 + threadIdx.x; i < n2; i += stride) {
        float4 v = ((const float4*)s2)[i];
        ushort4 o; o.x = f2bf(v.x); o.y = f2bf(v.y); o.z = f2bf(v.z); o.w = f2bf(v.w);
        ((ushort4*)d2)[i] = o;
    }
    for (int i = blockIdx.x * 256 + threadIdx.x; i < n3; i += stride) {
        float4 v = ((const float4*)s3)[i];
        ushort4 o; o.x = f2bf(v.x); o.y = f2bf(v.y); o.z = f2bf(v.z); o.w = f2bf(v.w);
        ((ushort4*)d3)[i] = o;
    }
}

// ---------------- LayerNorm -> bf16 ------------------------------------------
__global__ __launch_bounds__(256) void ln_kernel(const float* __restrict__ x,
                                                 const float* __restrict__ w,
                                                 const float* __restrict__ bvec,
                                                 unsigned short* __restrict__ out) {
    int t = blockIdx.x;
    int i = threadIdx.x;
    float v = x[t * DIMM + i];
    float s = v, s2 = v * v;
#pragma unroll
    for (int off = 1; off < 64; off <<= 1) {
        s  += __shfl_xor(s, off);
        s2 += __shfl_xor(s2, off);
    }
    __shared__ float ss[4], ss2[4];
    int wid = i >> 6;
    if ((i & 63) == 0) { ss[wid] = s; ss2[wid] = s2; }
    __syncthreads();
    s  = ss[0] + ss[1] + ss[2] + ss[3];
    s2 = ss2[0] + ss2[1] + ss2[2] + ss2[3];
    float mu  = s * (1.0f / DIMM);
    float var = s2 * (1.0f / DIMM) - mu * mu;
    float r   = rsqrtf(var + 1e-5f);
    out[t * DIMM + i] = f2bf((v - mu) * r * w[i] + bvec[i]);
}

// ---------------- bf16 MFMA NT GEMM ------------------------------------------
// Mode A (C1b != null): bf16 outputs, cols < nsplit -> C1b, else C2b (ldc each).
// Mode B (C1b == null): fp32 C (+resid).
#define TBM 128
#define TBN 64
#define TBK 32
#define LDKW (TBK + 8)
__global__ __launch_bounds__(256) void gemm_bf16(const unsigned short* __restrict__ A, int lda,
                                                 const unsigned short* __restrict__ Bw, int ldb,
                                                 const float* __restrict__ bias,
                                                 const float* __restrict__ resid,
                                                 float* __restrict__ C,
                                                 unsigned short* __restrict__ C1b,
                                                 unsigned short* __restrict__ C2b, int nsplit,
                                                 int ldc, int N, int K) {
    using short8  = __attribute__((ext_vector_type(8))) short;
    using floatx4 = __attribute__((ext_vector_type(4))) float;
    __shared__ __align__(16) unsigned short As[TBM * LDKW];
    __shared__ __align__(16) unsigned short Bs[TBN * LDKW];

    int tid  = threadIdx.x;
    int m0   = blockIdx.y * TBM;
    int n0   = blockIdx.x * TBN;
    int w    = tid >> 6;
    int lane = tid & 63;
    int wm   = (w & 1) * 64;
    int wn   = (w >> 1) * 32;
    int lr   = lane & 15;
    int quad = lane >> 4;

    floatx4 acc[4][2] = {};

    int ar = tid >> 1;
    int ak = (tid & 1) * 16;
    int br = tid >> 2;
    int bk = (tid & 3) * 8;

    for (int k0 = 0; k0 < K; k0 += TBK) {
        {
            const unsigned short* src = &A[(size_t)(m0 + ar) * lda + k0 + ak];
            int4 a0 = *(const int4*)(src);
            int4 a1 = *(const int4*)(src + 8);
            *(int4*)&As[ar * LDKW + ak]     = a0;
            *(int4*)&As[ar * LDKW + ak + 8] = a1;
        }
        {
            int gn = n0 + br;
            int4 b0 = make_int4(0, 0, 0, 0);
            if (gn < N) b0 = *(const int4*)&Bw[(size_t)gn * ldb + k0 + bk];
            *(int4*)&Bs[br * LDKW + bk] = b0;
        }
        __syncthreads();
        short8 af[4], bf[2];
#pragma unroll
        for (int i = 0; i < 4; ++i)
            af[i] = *(const short8*)&As[(wm + i * 16 + lr) * LDKW + quad * 8];
#pragma unroll
        for (int j = 0; j < 2; ++j)
            bf[j] = *(const short8*)&Bs[(wn + j * 16 + lr) * LDKW + quad * 8];
#pragma unroll
        for (int i = 0; i < 4; ++i)
#pragma unroll
            for (int j = 0; j < 2; ++j)
                acc[i][j] = __builtin_amdgcn_mfma_f32_16x16x32_bf16(af[i], bf[j], acc[i][j], 0, 0, 0);
        __syncthreads();
    }

#pragma unroll
    for (int j = 0; j < 2; ++j) {
        int cn = n0 + wn + j * 16 + lr;
        if (cn < N) {
            float bb = bias ? bias[cn] : 0.0f;
            if (C1b) {
                unsigned short* dst = (cn < nsplit) ? C1b : C2b;
                int col = (cn < nsplit) ? cn : cn - nsplit;
#pragma unroll
                for (int i = 0; i < 4; ++i)
#pragma unroll
                    for (int r = 0; r < 4; ++r) {
                        int cm = m0 + wm + i * 16 + quad * 4 + r;
                        dst[(size_t)cm * ldc + col] = f2bf(acc[i][j][r] + bb);
                    }
            } else {
#pragma unroll
                for (int i = 0; i < 4; ++i)
#pragma unroll
                    for (int r = 0; r < 4; ++r) {
                        int cm = m0 + wm + i * 16 + quad * 4 + r;
                        float v = acc[i][j][r] + bb;
                        if (resid) v += resid[(size_t)cm * ldc + cn];
                        C[(size_t)cm * ldc + cn] = v;
                    }
            }
        }
    }
}

// ---------------- Depthwise causal conv (4-tap) + SiLU, bf16 in/out ----------
__global__ __launch_bounds__(256) void conv_silu(const unsigned short* __restrict__ Xb,
                                                 const float* __restrict__ cw,
                                                 const float* __restrict__ cb,
                                                 unsigned short* __restrict__ xcb) {
    int idx = blockIdx.x * blockDim.x + threadIdx.x;
    int d = idx & (DIN - 1);
    int t = idx >> 9;
    int l = t & (LL - 1);
    int bq = t >> 9;
    float acc = cb[d];
#pragma unroll
    for (int k = 0; k < DCONV; ++k) {
        int ls = l - (DCONV - 1) + k;
        if (ls >= 0) acc += cw[d * DCONV + k] * bf2f(Xb[(size_t)(bq * LL + ls) * DIN + d]);
    }
    float v = acc / (1.0f + __expf(-acc));
    xcb[(size_t)t * DIN + d] = f2bf(v);
}

// ---------------- dt = softplus(dbc[:, :16] @ dtw^T + dtb) -> bf16 -----------
__global__ __launch_bounds__(256) void dt_kernel(const float* __restrict__ dbc,
                                                 const float* __restrict__ dtw,
                                                 const float* __restrict__ dtbias,
                                                 unsigned short* __restrict__ dtout) {
    int idx = blockIdx.x * blockDim.x + threadIdx.x;  // over TT*DIN
    int d = idx & (DIN - 1);
    int t = idx >> 9;
    float a = dtbias[d];
    const float4* wv = (const float4*)(dtw + d * DTRANK);
    const float* dr = dbc + (size_t)t * DBC_DIM;
#pragma unroll
    for (int q = 0; q < 4; ++q) {
        float4 w4 = wv[q];
        a += w4.x * dr[q * 4 + 0] + w4.y * dr[q * 4 + 1] +
             w4.z * dr[q * 4 + 2] + w4.w * dr[q * 4 + 3];
    }
    float sp = (a > 20.0f) ? a : log1pf(__expf(a));
    dtout[(size_t)t * DIN + d] = f2bf(sp);
}

// ---------------- Selective scan: state-split (2 thr/d, 8 states each) -------
// grid = BB*NC*4 blocks; block covers 128 d x 2 state-halves; CHUNK=16 steps.
// H layout: [sc][d][16].
__global__ __launch_bounds__(256) void scan_p1(const unsigned short* __restrict__ xcb,
                                               const unsigned short* __restrict__ dtb,
                                               const float* __restrict__ dbc,
                                               const float* __restrict__ A_log,
                                               float* __restrict__ S,
                                               float* __restrict__ H) {
    int bid = blockIdx.x;
    int dq = bid & 3;
    int c  = (bid >> 2) & (NC - 1);
    int b  = bid >> 7;
    int dloc = threadIdx.x >> 1;
    int sh   = threadIdx.x & 1;
    int d  = dq * 128 + dloc;
    int n0 = sh * 8;
    int base = b * LL + c * CHUNK;

    __shared__ float LB[CHUNK * DBC_DIM];
    for (int i = threadIdx.x; i < CHUNK * DBC_DIM / 4; i += 256)
        ((float4*)LB)[i] = ((const float4*)(dbc + (size_t)base * DBC_DIM))[i];

    float a[8];
    {
        const float4* ar = (const float4*)(A_log + d * DSTATE + n0);
        float4 v0 = ar[0], v1 = ar[1];
        a[0] = -__expf(v0.x); a[1] = -__expf(v0.y); a[2] = -__expf(v0.z); a[3] = -__expf(v0.w);
        a[4] = -__expf(v1.x); a[5] = -__expf(v1.y); a[6] = -__expf(v1.z); a[7] = -__expf(v1.w);
    }
    __syncthreads();

    float h[8];
#pragma unroll
    for (int j = 0; j < 8; ++j) h[j] = 0.0f;
    float Ssum = 0.0f;
    float u   = bf2f(xcb[(size_t)base * DIN + d]);
    float dtv = bf2f(dtb[(size_t)base * DIN + d]);
#pragma unroll 4
    for (int s = 0; s < CHUNK; ++s) {
        float nu  = bf2f(xcb[(size_t)(base + s + 1) * DIN + d]);
        float ndt = bf2f(dtb[(size_t)(base + s + 1) * DIN + d]);
        const float* row = &LB[s * DBC_DIM];
        Ssum += dtv;
        float wv = dtv * u;
#pragma unroll
        for (int j = 0; j < 8; ++j) {
            float dA = __expf(dtv * a[j]);
            h[j] = dA * h[j] + wv * row[DTRANK + n0 + j];
        }
        u = nu; dtv = ndt;
    }
    size_t sc = (size_t)b * NC + c;
    if (sh == 0) S[sc * DIN + d] = Ssum;
#pragma unroll
    for (int j = 0; j < 8; ++j) H[(sc * DIN + d) * 16 + n0 + j] = h[j];
}

// Phase2: thread per (b,d,n); serial over chunks; Hin overwrites H in place.
__global__ __launch_bounds__(256) void scan_p2(const float* __restrict__ A_log,
                                               const float* __restrict__ S,
                                               float* __restrict__ H) {
    int idx = blockIdx.x * 256 + threadIdx.x;   // BB*DIN*16
    int n = idx & 15;
    int d = (idx >> 4) & (DIN - 1);
    int b = idx >> 13;
    float a = -__expf(A_log[d * DSTATE + n]);
    float h = 0.0f;
#pragma unroll
    for (int c = 0; c < NC; ++c) {
        size_t sc = (size_t)b * NC + c;
        float Sv = S[sc * DIN + d];
        size_t q = (sc * DIN + d) * 16 + n;
        float Hc = H[q];
        H[q] = h;
        h = __expf(a * Sv) * h + Hc;
    }
}

// Phase3: state-split scan; fused y + g = y*silu(z) -> bf16.
__global__ __launch_bounds__(256) void scan_p3(const unsigned short* __restrict__ xcb,
                                               const unsigned short* __restrict__ dtb,
                                               const unsigned short* __restrict__ Zb,
                                               const float* __restrict__ dbc,
                                               const float* __restrict__ A_log,
                                               const float* __restrict__ Dp,
                                               const float* __restrict__ Hin,
                                               unsigned short* __restrict__ gb) {
    int bid = blockIdx.x;
    int dq = bid & 3;
    int c  = (bid >> 2) & (NC - 1);
    int b  = bid >> 7;
    int dloc = threadIdx.x >> 1;
    int sh   = threadIdx.x & 1;
    int d  = dq * 128 + dloc;
    int n0 = sh * 8;
    int base = b * LL + c * CHUNK;

    __shared__ float LB[CHUNK * DBC_DIM];
    for (int i = threadIdx.x; i < CHUNK * DBC_DIM / 4; i += 256)
        ((float4*)LB)[i] = ((const float4*)(dbc + (size_t)base * DBC_DIM))[i];

    float a[8];
    {
        const float4* ar = (const float4*)(A_log + d * DSTATE + n0);
        float4 v0 = ar[0], v1 = ar[1];
        a[0] = -__expf(v0.x); a[1] = -__expf(v0.y); a[2] = -__expf(v0.z); a[3] = -__expf(v0.w);
        a[4] = -__expf(v1.x); a[5] = -__expf(v1.y); a[6] = -__expf(v1.z); a[7] = -__expf(v1.w);
    }
    float Dd = Dp[d];
    size_t sc = (size_t)b * NC + c;
    float h[8];
#pragma unroll
    for (int j = 0; j < 8; ++j) h[j] = Hin[(sc * DIN + d) * 16 + n0 + j];
    __syncthreads();

    float u   = bf2f(xcb[(size_t)base * DIN + d]);
    float dtv = bf2f(dtb[(size_t)base * DIN + d]);
#pragma unroll 4
    for (int s = 0; s < CHUNK; ++s) {
        float nu  = bf2f(xcb[(size_t)(base + s + 1) * DIN + d]);
        float ndt = bf2f(dtb[(size_t)(base + s + 1) * DIN + d]);
        const float* row = &LB[s * DBC_DIM];
        float wv = dtv * u;
        float y  = (sh == 0) ? u * Dd : 0.0f;
#pragma unroll
        for (int j = 0; j < 8; ++j) {
            float dA = __expf(dtv * a[j]);
            h[j] = dA * h[j] + wv * row[DTRANK + n0 + j];
            y += h[j] * row[DTRANK + DSTATE + n0 + j];
        }
        y += __shfl_xor(y, 1);
        if (sh == 0) {
            float zf = bf2f(Zb[(size_t)(base + s) * DIN + d]);
            float g = y * (zf / (1.0f + __expf(-zf)));
            gb[(size_t)(base + s) * DIN + d] = f2bf(g);
        }
        u = nu; dtv = ndt;
    }
}

extern "C" void kernel_launch(void* const* d_in, const int* in_sizes, int n_in,
                              void* d_out, int out_size, void* d_ws, size_t ws_size,
                              hipStream_t stream) {
    const float* x_in   = (const float*)d_in[0];
    const float* ln_w   = (const float*)d_in[1];
    const float* ln_b   = (const float*)d_in[2];
    const float* in_w   = (const float*)d_in[3];
    const float* in_b   = (const float*)d_in[4];
    const float* conv_w = (const float*)d_in[5];
    const float* conv_b = (const float*)d_in[6];
    const float* xp_w   = (const float*)d_in[7];
    const float* dt_w   = (const float*)d_in[8];
    const float* dt_b   = (const float*)d_in[9];
    const float* A_log  = (const float*)d_in[10];
    const float* Dp     = (const float*)d_in[11];
    const float* ow     = (const float*)d_in[12];
    float* out = (float*)d_out;

    const size_t M = 1048576;
    float* ws = (float*)d_ws;
    float* xbuf = ws;                              // [0,2M) fp32 layer io
    unsigned short* hb  = (unsigned short*)(ws + 2 * M);   // [2M,3M) bf16 TT*256
    float* dbc = ws + 3 * M;                       // [3M,3.5M) fp32 TT*48
    unsigned short* Xb  = (unsigned short*)(ws + 4 * M);   // [4M,6M) bf16 TT*512
    unsigned short* Zb  = (unsigned short*)(ws + 6 * M);   // [6M,8M)
    unsigned short* xcb = (unsigned short*)(ws + 8 * M);   // [8M,10M)
    unsigned short* dtb = (unsigned short*)(ws + 10 * M);  // [10M,12M)
    unsigned short* gb  = (unsigned short*)(ws + 12 * M);  // [12M,14M)
    float* Hbuf = ws + 14 * M;                     // [14M,18M) BB*NC*DIN*16 = 4M
    float* Sbuf = ws + 18 * M;                     // [18M,18.25M) BB*NC*DIN = 256K
    unsigned short* inwb = (unsigned short*)(ws + 18 * M + 262144);
    unsigned short* owb  = inwb + (size_t)NB * XZ_DIM * DIMM;
    unsigned short* xpwb = owb + (size_t)NB * DIMM * DIN;

    cvt3_kernel<<<256, 256, 0, stream>>>(
        in_w, inwb, NB * XZ_DIM * DIMM / 4,
        ow,   owb,  NB * DIMM * DIN / 4,
        xp_w, xpwb, NB * DBC_DIM * DIN / 4);

    for (int layer = 0; layer < NB; ++layer) {
        const float* xi = (layer == 0) ? x_in : xbuf;
        float* xo = (layer == NB - 1) ? out : xbuf;

        ln_kernel<<<TT, 256, 0, stream>>>(xi, ln_w + layer * DIMM, ln_b + layer * DIMM, hb);

        // in_proj: both halves bf16 (X -> Xb, Z -> Zb)
        gemm_bf16<<<dim3(XZ_DIM / TBN, TT / TBM), 256, 0, stream>>>(
            hb, DIMM, inwb + (size_t)layer * XZ_DIM * DIMM, DIMM,
            in_b + layer * XZ_DIM, nullptr, nullptr, Xb, Zb, DIN, DIN, XZ_DIM, DIMM);

        conv_silu<<<(TT * DIN) / 256, 256, 0, stream>>>(
            Xb, conv_w + layer * DIN * DCONV, conv_b + layer * DIN, xcb);

        // x_proj: bf16 MFMA -> dbc fp32
        gemm_bf16<<<dim3(1, TT / TBM), 256, 0, stream>>>(
            xcb, DIN, xpwb + (size_t)layer * DBC_DIM * DIN, DIN,
            nullptr, nullptr, dbc, nullptr, nullptr, 0, DBC_DIM, DBC_DIM, DIN);

        dt_kernel<<<(TT * DIN) / 256, 256, 0, stream>>>(
            dbc, dt_w + (size_t)layer * DIN * DTRANK, dt_b + layer * DIN, dtb);

        const float* Al = A_log + (size_t)layer * DIN * DSTATE;
        scan_p1<<<BB * NC * 4, 256, 0, stream>>>(xcb, dtb, dbc, Al, Sbuf, Hbuf);
        scan_p2<<<(BB * DIN * 16) / 256, 256, 0, stream>>>(Al, Sbuf, Hbuf);
        scan_p3<<<BB * NC * 4, 256, 0, stream>>>(xcb, dtb, Zb, dbc, Al,
                                                 Dp + layer * DIN, Hbuf, gb);

        // out_proj: fp32 out + residual
        gemm_bf16<<<dim3(DIMM / TBN, TT / TBM), 256, 0, stream>>>(
            gb, DIN, owb + (size_t)layer * DIMM * DIN, DIN,
            nullptr, xi, xo, nullptr, nullptr, 0, DIMM, DIMM, DIN);
    }
}